// Round 1
// baseline (684.974 us; speedup 1.0000x reference)
//
#include <hip/hip_runtime.h>
#include <hip/hip_bf16.h>
#include <math.h>

typedef __hip_bfloat16 bf16;
typedef short bf16x8 __attribute__((ext_vector_type(8)));
typedef float f32x4 __attribute__((ext_vector_type(4)));

#define NB 8
#define LQ 3072
#define CC 768
#define NHEADS 6
#define NPTS 4
#define DHEAD 128
#define HLVL 64
#define WLVL 64
#define LIN 4096
#define HID 192
#define BLTOT 24576   // NB*LQ
#define FROWS 32768   // NB*LIN

// ---------------- LayerNorm (f32 in) -> bf16 out, C=768, 256 thr/row ----------------
__global__ __launch_bounds__(256)
void ln_bf16_kernel(const float* __restrict__ x, const float* __restrict__ w,
                    const float* __restrict__ b, bf16* __restrict__ out)
{
    const int row = blockIdx.x;
    const int t = threadIdx.x;
    const float* xr = x + (size_t)row * CC;
    float v0 = xr[t], v1 = xr[t + 256], v2 = xr[t + 512];
    float s = v0 + v1 + v2;
    float ss = v0 * v0 + v1 * v1 + v2 * v2;
    #pragma unroll
    for (int o = 32; o > 0; o >>= 1) {
        s += __shfl_down(s, o);
        ss += __shfl_down(ss, o);
    }
    __shared__ float red[8];
    const int lane = t & 63, wv = t >> 6;
    if (lane == 0) { red[wv] = s; red[4 + wv] = ss; }
    __syncthreads();
    if (t == 0) {
        float S = red[0] + red[1] + red[2] + red[3];
        float SS = red[4] + red[5] + red[6] + red[7];
        float m = S * (1.f / CC);
        float var = SS * (1.f / CC) - m * m;
        red[0] = m; red[1] = rsqrtf(var + 1e-6f);
    }
    __syncthreads();
    const float m = red[0], rs = red[1];
    bf16* o = out + (size_t)row * CC;
    o[t]       = __float2bfloat16((v0 - m) * rs * w[t] + b[t]);
    o[t + 256] = __float2bfloat16((v1 - m) * rs * w[t + 256] + b[t + 256]);
    o[t + 512] = __float2bfloat16((v2 - m) * rs * w[t + 512] + b[t + 512]);
}

// ---------------- weight f32 (K,N) -> bf16 transposed (N,K) ----------------
__global__ __launch_bounds__(256)
void wt_bf16_kernel(const float* __restrict__ src, bf16* __restrict__ dst, int K, int N)
{
    int i = blockIdx.x * 256 + threadIdx.x;
    if (i < K * N) {
        int n = i / K, k = i - n * K;
        dst[i] = __float2bfloat16(src[(size_t)k * N + n]);
    }
}

// ---------------- combined sampling-offset/attn-weight projection, padded to N=128 ----------------
__global__ __launch_bounds__(256)
void build_dots_w(const float* __restrict__ so_w, const float* __restrict__ so_b,
                  const float* __restrict__ aw_w, const float* __restrict__ aw_b,
                  bf16* __restrict__ wt, float* __restrict__ db)
{
    int i = blockIdx.x * 256 + threadIdx.x;  // over 128*768
    if (i < 128 * 768) {
        int n = i / 768, k = i - n * 768;
        float v = 0.f;
        if (n < 48) v = so_w[(size_t)k * 48 + n];
        else if (n < 72) v = aw_w[(size_t)k * 24 + (n - 48)];
        wt[i] = __float2bfloat16(v);
    }
    if (i < 128) {
        float bv = 0.f;
        if (i < 48) bv = so_b[i];
        else if (i < 72) bv = aw_b[i - 48];
        db[i] = bv;
    }
}

// ---------------- bf16 MFMA GEMM: C = A(M,K) * Bt(N,K)^T + bias (+res) ----------------
// MODE 0: bf16 out = acc+bias ; MODE 1: f32 out = acc+bias+res ; MODE 2: f32 out = acc+bias
template<int BM, int BN, int BK, int WM, int WN, int MODE>
__global__ __launch_bounds__(256)
void gemm_kernel(const bf16* __restrict__ A, const bf16* __restrict__ Bt,
                 const float* __restrict__ bias, const float* res,
                 void* outv, int M, int N, int K)
{
    static_assert(BK == 64, "staging math assumes BK=64");
    constexpr int LDK = BK + 8;                 // +8 bf16 pad: 2-way (free) bank aliasing
    constexpr int WAVES_N = BN / WN;
    constexpr int FM = WM / 16, FN = WN / 16;
    constexpr int CH_A = (BM * BK) / (256 * 8);
    constexpr int CH_B = (BN * BK) / (256 * 8);
    __shared__ bf16 sA[BM * LDK];
    __shared__ bf16 sB[BN * LDK];
    const int tid = threadIdx.x;
    const int lane = tid & 63;
    const int wave = tid >> 6;
    const int wm = (wave / WAVES_N) * WM;
    const int wn = (wave % WAVES_N) * WN;
    const int m0 = blockIdx.y * BM;
    const int n0 = blockIdx.x * BN;

    f32x4 acc[FM][FN] = {};

    for (int k0 = 0; k0 < K; k0 += BK) {
        #pragma unroll
        for (int i = 0; i < CH_A; ++i) {
            int chunk = i * 256 + tid;
            int row = chunk >> 3;               // 8 x 16B chunks per 64-el row
            int col = (chunk & 7) * 8;
            *(int4*)(&sA[row * LDK + col]) = *(const int4*)(A + (size_t)(m0 + row) * K + k0 + col);
        }
        #pragma unroll
        for (int i = 0; i < CH_B; ++i) {
            int chunk = i * 256 + tid;
            int row = chunk >> 3;
            int col = (chunk & 7) * 8;
            *(int4*)(&sB[row * LDK + col]) = *(const int4*)(Bt + (size_t)(n0 + row) * K + k0 + col);
        }
        __syncthreads();
        #pragma unroll
        for (int kk = 0; kk < BK; kk += 32) {
            const int krow = kk + ((lane >> 4) << 3);
            bf16x8 aF[FM], bF[FN];
            #pragma unroll
            for (int i = 0; i < FM; ++i)
                aF[i] = *(const bf16x8*)(&sA[(wm + i * 16 + (lane & 15)) * LDK + krow]);
            #pragma unroll
            for (int j = 0; j < FN; ++j)
                bF[j] = *(const bf16x8*)(&sB[(wn + j * 16 + (lane & 15)) * LDK + krow]);
            #pragma unroll
            for (int i = 0; i < FM; ++i) {
                #pragma unroll
                for (int j = 0; j < FN; ++j)
                    acc[i][j] = __builtin_amdgcn_mfma_f32_16x16x32_bf16(aF[i], bF[j], acc[i][j], 0, 0, 0);
            }
        }
        __syncthreads();
    }

    #pragma unroll
    for (int i = 0; i < FM; ++i) {
        #pragma unroll
        for (int j = 0; j < FN; ++j) {
            const int colg = n0 + wn + j * 16 + (lane & 15);
            #pragma unroll
            for (int r = 0; r < 4; ++r) {
                const int rowg = m0 + wm + i * 16 + ((lane >> 4) << 2) + r;
                float v = acc[i][j][r] + bias[colg];
                size_t idx = (size_t)rowg * N + colg;
                if constexpr (MODE == 0)      ((bf16*)outv)[idx] = __float2bfloat16(v);
                else if constexpr (MODE == 1) ((float*)outv)[idx] = v + res[idx];
                else                          ((float*)outv)[idx] = v;
            }
        }
    }
}

// ---------------- softmax over 4 pts + sampling locations ----------------
__global__ __launch_bounds__(256)
void locsoftmax_kernel(const float* __restrict__ dots, const float* __restrict__ refp,
                       float4* __restrict__ params)
{
    int i = blockIdx.x * 256 + threadIdx.x;
    if (i >= BLTOT * NHEADS) return;
    int bl = i / NHEADS, h = i - bl * NHEADS;
    const float* d = dots + (size_t)bl * 128;
    float rx = refp[(size_t)bl * 2], ry = refp[(size_t)bl * 2 + 1];
    float l0 = d[48 + h * 4 + 0], l1 = d[48 + h * 4 + 1];
    float l2 = d[48 + h * 4 + 2], l3 = d[48 + h * 4 + 3];
    float mx = fmaxf(fmaxf(l0, l1), fmaxf(l2, l3));
    float e0 = expf(l0 - mx), e1 = expf(l1 - mx), e2 = expf(l2 - mx), e3 = expf(l3 - mx);
    float inv = 1.f / (e0 + e1 + e2 + e3);
    float ee[4] = {e0, e1, e2, e3};
    #pragma unroll
    for (int p = 0; p < 4; ++p) {
        float ox = d[h * 8 + p * 2], oy = d[h * 8 + p * 2 + 1];
        params[(size_t)i * 4 + p] =
            make_float4(rx + ox * (1.f / WLVL), ry + oy * (1.f / HLVL), ee[p] * inv, 0.f);
    }
}

// ---------------- bilinear sample + attention-weighted sum ----------------
__global__ __launch_bounds__(256)
void sampler_kernel(const bf16* __restrict__ value, const float4* __restrict__ params,
                    bf16* __restrict__ attn_in)
{
    const int bl = blockIdx.x;
    const int b = bl / LQ;
    const int tid = threadIdx.x;
    const int c = tid & 127;
    const int hh = tid >> 7;                    // 0/1: two heads per pass
    const bf16* vb = value + (size_t)b * LIN * CC;
    #pragma unroll
    for (int it = 0; it < 3; ++it) {
        const int h = it * 2 + hh;
        const bf16* vh = vb + h * DHEAD + c;
        float acc = 0.f;
        #pragma unroll
        for (int p = 0; p < NPTS; ++p) {
            float4 pr = params[(size_t)bl * 24 + h * 4 + p];
            float x = pr.x * (float)WLVL - 0.5f;
            float y = pr.y * (float)HLVL - 0.5f;
            float x0f = floorf(x), y0f = floorf(y);
            float wx1 = x - x0f, wy1 = y - y0f;
            float wx0 = 1.f - wx1, wy0 = 1.f - wy1;
            int x0 = (int)x0f, y0 = (int)y0f;
            float aw = pr.z;
            #pragma unroll
            for (int dy = 0; dy < 2; ++dy) {
                int yi = y0 + dy;
                if (yi < 0 || yi >= HLVL) continue;
                float wy = dy ? wy1 : wy0;
                #pragma unroll
                for (int dx = 0; dx < 2; ++dx) {
                    int xi = x0 + dx;
                    if (xi < 0 || xi >= WLVL) continue;
                    float wgt = wy * (dx ? wx1 : wx0);
                    float v = __bfloat162float(vh[(size_t)(yi * WLVL + xi) * CC]);
                    acc += aw * wgt * v;
                }
            }
        }
        attn_in[(size_t)bl * CC + h * DHEAD + c] = __float2bfloat16(acc);
    }
}

// ---------------- depthwise 3x3 conv + bias + exact GELU ----------------
__global__ void dwconv_gelu_kernel(const float* __restrict__ z, const float* __restrict__ dw_w,
                                   const float* __restrict__ dw_b, bf16* __restrict__ g)
{
    const int m = blockIdx.x;                   // row in (B*Lq)
    const int c = threadIdx.x;                  // 192 channels
    const int pix = m & 1023;
    const int h = pix >> 5, w = pix & 31;
    float acc = dw_b[c];
    #pragma unroll
    for (int dy = -1; dy <= 1; ++dy) {
        int hh2 = h + dy;
        if (hh2 < 0 || hh2 >= 32) continue;
        #pragma unroll
        for (int dx = -1; dx <= 1; ++dx) {
            int ww2 = w + dx;
            if (ww2 < 0 || ww2 >= 32) continue;
            acc += z[(size_t)(m + dy * 32 + dx) * HID + c] * dw_w[c * 9 + (dy + 1) * 3 + (dx + 1)];
        }
    }
    float ge = acc * 0.5f * (1.f + erff(acc * 0.70710678118f));
    g[(size_t)m * HID + c] = __float2bfloat16(ge);
}

extern "C" void kernel_launch(void* const* d_in, const int* in_sizes, int n_in,
                              void* d_out, int out_size, void* d_ws, size_t ws_size,
                              hipStream_t stream)
{
    const float* query = (const float*)d_in[0];
    const float* refp  = (const float*)d_in[1];
    const float* feat  = (const float*)d_in[2];
    const float* qn_w = (const float*)d_in[7];
    const float* qn_b = (const float*)d_in[8];
    const float* fn_w = (const float*)d_in[9];
    const float* fn_b = (const float*)d_in[10];
    const float* so_w = (const float*)d_in[11];
    const float* so_b = (const float*)d_in[12];
    const float* aw_w = (const float*)d_in[13];
    const float* aw_b = (const float*)d_in[14];
    const float* vp_w = (const float*)d_in[15];
    const float* vp_b = (const float*)d_in[16];
    const float* op_w = (const float*)d_in[17];
    const float* op_b = (const float*)d_in[18];
    const float* ffn_w = (const float*)d_in[19];
    const float* ffn_b = (const float*)d_in[20];
    const float* fc1_w = (const float*)d_in[21];
    const float* fc1_b = (const float*)d_in[22];
    const float* dw_w = (const float*)d_in[23];
    const float* dw_b = (const float*)d_in[24];
    const float* fc2_w = (const float*)d_in[25];
    const float* fc2_b = (const float*)d_in[26];
    float* out = (float*)d_out;

    // ---- workspace layout (all 256B aligned) ----
    if (ws_size < (size_t)125829632) return;    // need ~126MB
    char* ws = (char*)d_ws;
    bf16* vp_wt   = (bf16*)(ws + 0);            // 768x768
    bf16* op_wt   = (bf16*)(ws + 1179648);      // 768x768
    bf16* fc1_wt  = (bf16*)(ws + 2359296);      // 192x768
    bf16* fc2_wt  = (bf16*)(ws + 2654208);      // 768x192
    bf16* dots_wt = (bf16*)(ws + 2949120);      // 128x768
    float* dots_b = (float*)(ws + 3145728);     // 128
    float4* params = (float4*)(ws + 3146240);   // 24576*24 float4
    float* dots_out = (float*)(ws + 12583424);  // 24576*128 f32
    char* regA = ws + 25166336;                 // 50.3MB: f_ln -> attn_in -> z
    char* regB = ws + 75497984;                 // 50.3MB: q_ln -> value -> y -> g
    bf16* f_ln    = (bf16*)regA;
    bf16* attn_in = (bf16*)regA;
    float* z      = (float*)regA;
    bf16* q_ln  = (bf16*)regB;
    bf16* value = (bf16*)regB;
    bf16* y     = (bf16*)regB;
    bf16* g     = (bf16*)regB;

    // ---- weight prep (bf16, transposed to (N,K)) ----
    wt_bf16_kernel<<<2304, 256, 0, stream>>>(vp_w, vp_wt, 768, 768);
    wt_bf16_kernel<<<2304, 256, 0, stream>>>(op_w, op_wt, 768, 768);
    wt_bf16_kernel<<<576, 256, 0, stream>>>(fc1_w, fc1_wt, 768, 192);
    wt_bf16_kernel<<<576, 256, 0, stream>>>(fc2_w, fc2_wt, 192, 768);
    build_dots_w<<<384, 256, 0, stream>>>(so_w, so_b, aw_w, aw_b, dots_wt, dots_b);

    // ---- MSDeformAttn ----
    ln_bf16_kernel<<<BLTOT, 256, 0, stream>>>(query, qn_w, qn_b, q_ln);
    gemm_kernel<128, 128, 64, 64, 64, 2><<<dim3(1, BLTOT / 128), 256, 0, stream>>>(
        q_ln, dots_wt, dots_b, nullptr, dots_out, BLTOT, 128, 768);
    locsoftmax_kernel<<<(BLTOT * NHEADS + 255) / 256, 256, 0, stream>>>(dots_out, refp, params);
    ln_bf16_kernel<<<FROWS, 256, 0, stream>>>(feat, fn_w, fn_b, f_ln);
    gemm_kernel<128, 128, 64, 64, 64, 0><<<dim3(6, FROWS / 128), 256, 0, stream>>>(
        f_ln, vp_wt, vp_b, nullptr, value, FROWS, 768, 768);
    sampler_kernel<<<BLTOT, 256, 0, stream>>>(value, params, attn_in);
    gemm_kernel<128, 128, 64, 64, 64, 1><<<dim3(6, BLTOT / 128), 256, 0, stream>>>(
        attn_in, op_wt, op_b, query, out, BLTOT, 768, 768);

    // ---- ConvFFN ----
    ln_bf16_kernel<<<BLTOT, 256, 0, stream>>>(out, ffn_w, ffn_b, y);
    gemm_kernel<128, 64, 64, 32, 64, 2><<<dim3(3, BLTOT / 128), 256, 0, stream>>>(
        y, fc1_wt, fc1_b, nullptr, z, BLTOT, HID, 768);
    dwconv_gelu_kernel<<<BLTOT, HID, 0, stream>>>(z, dw_w, dw_b, g);
    gemm_kernel<128, 128, 64, 64, 64, 1><<<dim3(6, BLTOT / 128), 256, 0, stream>>>(
        g, fc2_wt, fc2_b, out, out, BLTOT, 768, HID);
}

// Round 2
// 513.873 us; speedup vs baseline: 1.3330x; 1.3330x over previous
//
#include <hip/hip_runtime.h>
#include <hip/hip_bf16.h>
#include <math.h>

typedef __hip_bfloat16 bf16;
typedef short bf16x8 __attribute__((ext_vector_type(8)));
typedef float f32x4 __attribute__((ext_vector_type(4)));

#define NB 8
#define LQ 3072
#define CC 768
#define NHEADS 6
#define NPTS 4
#define DHEAD 128
#define HLVL 64
#define WLVL 64
#define LIN 4096
#define HID 192
#define BLTOT 24576   // NB*LQ
#define FROWS 32768   // NB*LIN

// ---------------- LayerNorm (f32 in) -> bf16 out, C=768, 256 thr/row ----------------
__global__ __launch_bounds__(256)
void ln_bf16_kernel(const float* __restrict__ x, const float* __restrict__ w,
                    const float* __restrict__ b, bf16* __restrict__ out)
{
    const int row = blockIdx.x;
    const int t = threadIdx.x;
    const float* xr = x + (size_t)row * CC;
    float v0 = xr[t], v1 = xr[t + 256], v2 = xr[t + 512];
    float s = v0 + v1 + v2;
    float ss = v0 * v0 + v1 * v1 + v2 * v2;
    #pragma unroll
    for (int o = 32; o > 0; o >>= 1) {
        s += __shfl_down(s, o);
        ss += __shfl_down(ss, o);
    }
    __shared__ float red[8];
    const int lane = t & 63, wv = t >> 6;
    if (lane == 0) { red[wv] = s; red[4 + wv] = ss; }
    __syncthreads();
    if (t == 0) {
        float S = red[0] + red[1] + red[2] + red[3];
        float SS = red[4] + red[5] + red[6] + red[7];
        float m = S * (1.f / CC);
        float var = SS * (1.f / CC) - m * m;
        red[0] = m; red[1] = rsqrtf(var + 1e-6f);
    }
    __syncthreads();
    const float m = red[0], rs = red[1];
    bf16* o = out + (size_t)row * CC;
    o[t]       = __float2bfloat16((v0 - m) * rs * w[t] + b[t]);
    o[t + 256] = __float2bfloat16((v1 - m) * rs * w[t + 256] + b[t + 256]);
    o[t + 512] = __float2bfloat16((v2 - m) * rs * w[t + 512] + b[t + 512]);
}

// ---------------- weight f32 (K,N) -> bf16 transposed (N,K) ----------------
__global__ __launch_bounds__(256)
void wt_bf16_kernel(const float* __restrict__ src, bf16* __restrict__ dst, int K, int N)
{
    int i = blockIdx.x * 256 + threadIdx.x;
    if (i < K * N) {
        int n = i / K, k = i - n * K;
        dst[i] = __float2bfloat16(src[(size_t)k * N + n]);
    }
}

// ---------------- combined sampling-offset/attn-weight projection, padded to N=128 ----------------
__global__ __launch_bounds__(256)
void build_dots_w(const float* __restrict__ so_w, const float* __restrict__ so_b,
                  const float* __restrict__ aw_w, const float* __restrict__ aw_b,
                  bf16* __restrict__ wt, float* __restrict__ db)
{
    int i = blockIdx.x * 256 + threadIdx.x;  // over 128*768
    if (i < 128 * 768) {
        int n = i / 768, k = i - n * 768;
        float v = 0.f;
        if (n < 48) v = so_w[(size_t)k * 48 + n];
        else if (n < 72) v = aw_w[(size_t)k * 24 + (n - 48)];
        wt[i] = __float2bfloat16(v);
    }
    if (i < 128) {
        float bv = 0.f;
        if (i < 48) bv = so_b[i];
        else if (i < 72) bv = aw_b[i - 48];
        db[i] = bv;
    }
}

// ---------------- bf16 MFMA GEMM: C = A(M,K) * Bt(N,K)^T + bias (+res) ----------------
// MODE 0: bf16 out = acc+bias ; MODE 1: f32 out = acc+bias+res ; MODE 2: f32 out = acc+bias
template<int BM, int BN, int BK, int WM, int WN, int MODE>
__global__ __launch_bounds__(256)
void gemm_kernel(const bf16* __restrict__ A, const bf16* __restrict__ Bt,
                 const float* __restrict__ bias, const float* res,
                 void* outv, int M, int N, int K)
{
    static_assert(BK == 64, "staging math assumes BK=64");
    constexpr int LDK = BK + 8;                 // +8 bf16 pad: 2-way (free) bank aliasing
    constexpr int WAVES_N = BN / WN;
    constexpr int FM = WM / 16, FN = WN / 16;
    constexpr int CH_A = (BM * BK) / (256 * 8);
    constexpr int CH_B = (BN * BK) / (256 * 8);
    __shared__ bf16 sA[BM * LDK];
    __shared__ bf16 sB[BN * LDK];
    const int tid = threadIdx.x;
    const int lane = tid & 63;
    const int wave = tid >> 6;
    const int wm = (wave / WAVES_N) * WM;
    const int wn = (wave % WAVES_N) * WN;
    const int m0 = blockIdx.y * BM;
    const int n0 = blockIdx.x * BN;

    f32x4 acc[FM][FN] = {};

    for (int k0 = 0; k0 < K; k0 += BK) {
        #pragma unroll
        for (int i = 0; i < CH_A; ++i) {
            int chunk = i * 256 + tid;
            int row = chunk >> 3;               // 8 x 16B chunks per 64-el row
            int col = (chunk & 7) * 8;
            *(int4*)(&sA[row * LDK + col]) = *(const int4*)(A + (size_t)(m0 + row) * K + k0 + col);
        }
        #pragma unroll
        for (int i = 0; i < CH_B; ++i) {
            int chunk = i * 256 + tid;
            int row = chunk >> 3;
            int col = (chunk & 7) * 8;
            *(int4*)(&sB[row * LDK + col]) = *(const int4*)(Bt + (size_t)(n0 + row) * K + k0 + col);
        }
        __syncthreads();
        #pragma unroll
        for (int kk = 0; kk < BK; kk += 32) {
            const int krow = kk + ((lane >> 4) << 3);
            bf16x8 aF[FM], bF[FN];
            #pragma unroll
            for (int i = 0; i < FM; ++i)
                aF[i] = *(const bf16x8*)(&sA[(wm + i * 16 + (lane & 15)) * LDK + krow]);
            #pragma unroll
            for (int j = 0; j < FN; ++j)
                bF[j] = *(const bf16x8*)(&sB[(wn + j * 16 + (lane & 15)) * LDK + krow]);
            #pragma unroll
            for (int i = 0; i < FM; ++i) {
                #pragma unroll
                for (int j = 0; j < FN; ++j)
                    acc[i][j] = __builtin_amdgcn_mfma_f32_16x16x32_bf16(aF[i], bF[j], acc[i][j], 0, 0, 0);
            }
        }
        __syncthreads();
    }

    #pragma unroll
    for (int i = 0; i < FM; ++i) {
        #pragma unroll
        for (int j = 0; j < FN; ++j) {
            const int colg = n0 + wn + j * 16 + (lane & 15);
            #pragma unroll
            for (int r = 0; r < 4; ++r) {
                const int rowg = m0 + wm + i * 16 + ((lane >> 4) << 2) + r;
                float v = acc[i][j][r] + bias[colg];
                size_t idx = (size_t)rowg * N + colg;
                if constexpr (MODE == 0)      ((bf16*)outv)[idx] = __float2bfloat16(v);
                else if constexpr (MODE == 1) ((float*)outv)[idx] = v + res[idx];
                else                          ((float*)outv)[idx] = v;
            }
        }
    }
}

// ---------------- softmax over 4 pts + sampling locations ----------------
__global__ __launch_bounds__(256)
void locsoftmax_kernel(const float* __restrict__ dots, const float* __restrict__ refp,
                       float4* __restrict__ params)
{
    int i = blockIdx.x * 256 + threadIdx.x;
    if (i >= BLTOT * NHEADS) return;
    int bl = i / NHEADS, h = i - bl * NHEADS;
    const float* d = dots + (size_t)bl * 128;
    float rx = refp[(size_t)bl * 2], ry = refp[(size_t)bl * 2 + 1];
    float l0 = d[48 + h * 4 + 0], l1 = d[48 + h * 4 + 1];
    float l2 = d[48 + h * 4 + 2], l3 = d[48 + h * 4 + 3];
    float mx = fmaxf(fmaxf(l0, l1), fmaxf(l2, l3));
    float e0 = expf(l0 - mx), e1 = expf(l1 - mx), e2 = expf(l2 - mx), e3 = expf(l3 - mx);
    float inv = 1.f / (e0 + e1 + e2 + e3);
    float ee[4] = {e0, e1, e2, e3};
    #pragma unroll
    for (int p = 0; p < 4; ++p) {
        float ox = d[h * 8 + p * 2], oy = d[h * 8 + p * 2 + 1];
        params[(size_t)i * 4 + p] =
            make_float4(rx + ox * (1.f / WLVL), ry + oy * (1.f / HLVL), ee[p] * inv, 0.f);
    }
}

// ---------------- bilinear sample + attention-weighted sum (vectorized: 16 lanes x 8ch per q-head) ----------------
__global__ __launch_bounds__(256)
void sampler_kernel(const bf16* __restrict__ value, const float4* __restrict__ params,
                    bf16* __restrict__ attn_in)
{
    const int tid = threadIdx.x;
    const int g = blockIdx.x * 16 + (tid >> 4);     // query-head index = bl*NHEADS + h
    const int lane16 = tid & 15;
    const int bl = g / NHEADS;
    const int h = g - bl * NHEADS;
    const int b = bl / LQ;
    const int c = lane16 * 8;                       // 8 channels per lane
    const bf16* vh = value + (size_t)b * LIN * CC + h * DHEAD + c;

    float acc[8] = {};
    #pragma unroll
    for (int p = 0; p < NPTS; ++p) {
        float4 pr = params[(size_t)g * 4 + p];
        float x = pr.x * (float)WLVL - 0.5f;
        float y = pr.y * (float)HLVL - 0.5f;
        float x0f = floorf(x), y0f = floorf(y);
        float wx1 = x - x0f, wy1 = y - y0f;
        float wx0 = 1.f - wx1, wy0 = 1.f - wy1;
        int x0 = (int)x0f, y0 = (int)y0f;
        float aw = pr.z;
        #pragma unroll
        for (int dy = 0; dy < 2; ++dy) {
            int yi = y0 + dy;
            if (yi < 0 || yi >= HLVL) continue;
            float wy = dy ? wy1 : wy0;
            #pragma unroll
            for (int dx = 0; dx < 2; ++dx) {
                int xi = x0 + dx;
                if (xi < 0 || xi >= WLVL) continue;
                float wgt = aw * wy * (dx ? wx1 : wx0);
                bf16x8 v = *(const bf16x8*)(vh + (size_t)(yi * WLVL + xi) * CC);
                #pragma unroll
                for (int j = 0; j < 8; ++j)
                    acc[j] += wgt * __uint_as_float(((unsigned)(unsigned short)v[j]) << 16);
            }
        }
    }
    bf16 tmp[8];
    #pragma unroll
    for (int j = 0; j < 8; ++j) tmp[j] = __float2bfloat16(acc[j]);
    *(bf16x8*)(attn_in + (size_t)bl * CC + h * DHEAD + c) = *(bf16x8*)tmp;
}

// ---------------- depthwise 3x3 conv + bias + exact GELU ----------------
__global__ void dwconv_gelu_kernel(const float* __restrict__ z, const float* __restrict__ dw_w,
                                   const float* __restrict__ dw_b, bf16* __restrict__ g)
{
    const int m = blockIdx.x;                   // row in (B*Lq)
    const int c = threadIdx.x;                  // 192 channels
    const int pix = m & 1023;
    const int h = pix >> 5, w = pix & 31;
    float acc = dw_b[c];
    #pragma unroll
    for (int dy = -1; dy <= 1; ++dy) {
        int hh2 = h + dy;
        if (hh2 < 0 || hh2 >= 32) continue;
        #pragma unroll
        for (int dx = -1; dx <= 1; ++dx) {
            int ww2 = w + dx;
            if (ww2 < 0 || ww2 >= 32) continue;
            acc += z[(size_t)(m + dy * 32 + dx) * HID + c] * dw_w[c * 9 + (dy + 1) * 3 + (dx + 1)];
        }
    }
    float ge = acc * 0.5f * (1.f + erff(acc * 0.70710678118f));
    g[(size_t)m * HID + c] = __float2bfloat16(ge);
}

extern "C" void kernel_launch(void* const* d_in, const int* in_sizes, int n_in,
                              void* d_out, int out_size, void* d_ws, size_t ws_size,
                              hipStream_t stream)
{
    const float* query = (const float*)d_in[0];
    const float* refp  = (const float*)d_in[1];
    const float* feat  = (const float*)d_in[2];
    const float* qn_w = (const float*)d_in[7];
    const float* qn_b = (const float*)d_in[8];
    const float* fn_w = (const float*)d_in[9];
    const float* fn_b = (const float*)d_in[10];
    const float* so_w = (const float*)d_in[11];
    const float* so_b = (const float*)d_in[12];
    const float* aw_w = (const float*)d_in[13];
    const float* aw_b = (const float*)d_in[14];
    const float* vp_w = (const float*)d_in[15];
    const float* vp_b = (const float*)d_in[16];
    const float* op_w = (const float*)d_in[17];
    const float* op_b = (const float*)d_in[18];
    const float* ffn_w = (const float*)d_in[19];
    const float* ffn_b = (const float*)d_in[20];
    const float* fc1_w = (const float*)d_in[21];
    const float* fc1_b = (const float*)d_in[22];
    const float* dw_w = (const float*)d_in[23];
    const float* dw_b = (const float*)d_in[24];
    const float* fc2_w = (const float*)d_in[25];
    const float* fc2_b = (const float*)d_in[26];
    float* out = (float*)d_out;

    // ---- workspace layout (all 256B aligned) ----
    if (ws_size < (size_t)125829632) return;    // need ~126MB
    char* ws = (char*)d_ws;
    bf16* vp_wt   = (bf16*)(ws + 0);            // 768x768
    bf16* op_wt   = (bf16*)(ws + 1179648);      // 768x768
    bf16* fc1_wt  = (bf16*)(ws + 2359296);      // 192x768
    bf16* fc2_wt  = (bf16*)(ws + 2654208);      // 768x192
    bf16* dots_wt = (bf16*)(ws + 2949120);      // 128x768
    float* dots_b = (float*)(ws + 3145728);     // 128
    float4* params = (float4*)(ws + 3146240);   // 24576*24 float4
    float* dots_out = (float*)(ws + 12583424);  // 24576*128 f32
    char* regA = ws + 25166336;                 // 50.3MB: f_ln -> attn_in -> z
    char* regB = ws + 75497984;                 // 50.3MB: q_ln -> value -> y -> g
    bf16* f_ln    = (bf16*)regA;
    bf16* attn_in = (bf16*)regA;
    float* z      = (float*)regA;
    bf16* q_ln  = (bf16*)regB;
    bf16* value = (bf16*)regB;
    bf16* y     = (bf16*)regB;
    bf16* g     = (bf16*)regB;

    // ---- weight prep (bf16, transposed to (N,K)) ----
    wt_bf16_kernel<<<2304, 256, 0, stream>>>(vp_w, vp_wt, 768, 768);
    wt_bf16_kernel<<<2304, 256, 0, stream>>>(op_w, op_wt, 768, 768);
    wt_bf16_kernel<<<576, 256, 0, stream>>>(fc1_w, fc1_wt, 768, 192);
    wt_bf16_kernel<<<576, 256, 0, stream>>>(fc2_w, fc2_wt, 192, 768);
    build_dots_w<<<384, 256, 0, stream>>>(so_w, so_b, aw_w, aw_b, dots_wt, dots_b);

    // ---- MSDeformAttn ----
    ln_bf16_kernel<<<BLTOT, 256, 0, stream>>>(query, qn_w, qn_b, q_ln);
    gemm_kernel<128, 128, 64, 64, 64, 2><<<dim3(1, BLTOT / 128), 256, 0, stream>>>(
        q_ln, dots_wt, dots_b, nullptr, dots_out, BLTOT, 128, 768);
    locsoftmax_kernel<<<(BLTOT * NHEADS + 255) / 256, 256, 0, stream>>>(dots_out, refp, params);
    ln_bf16_kernel<<<FROWS, 256, 0, stream>>>(feat, fn_w, fn_b, f_ln);
    gemm_kernel<128, 128, 64, 64, 64, 0><<<dim3(6, FROWS / 128), 256, 0, stream>>>(
        f_ln, vp_wt, vp_b, nullptr, value, FROWS, 768, 768);
    sampler_kernel<<<(BLTOT * NHEADS) / 16, 256, 0, stream>>>(value, params, attn_in);
    gemm_kernel<128, 128, 64, 64, 64, 1><<<dim3(6, BLTOT / 128), 256, 0, stream>>>(
        attn_in, op_wt, op_b, query, out, BLTOT, 768, 768);

    // ---- ConvFFN ----
    ln_bf16_kernel<<<BLTOT, 256, 0, stream>>>(out, ffn_w, ffn_b, y);
    gemm_kernel<128, 64, 64, 32, 64, 2><<<dim3(3, BLTOT / 128), 256, 0, stream>>>(
        y, fc1_wt, fc1_b, nullptr, z, BLTOT, HID, 768);
    dwconv_gelu_kernel<<<BLTOT, HID, 0, stream>>>(z, dw_w, dw_b, g);
    gemm_kernel<128, 128, 64, 64, 64, 1><<<dim3(6, BLTOT / 128), 256, 0, stream>>>(
        g, fc2_wt, fc2_b, out, out, BLTOT, 768, HID);
}

// Round 3
// 481.529 us; speedup vs baseline: 1.4225x; 1.0672x over previous
//
#include <hip/hip_runtime.h>
#include <hip/hip_bf16.h>
#include <math.h>

typedef __hip_bfloat16 bf16;
typedef short bf16x8 __attribute__((ext_vector_type(8)));
typedef float f32x4 __attribute__((ext_vector_type(4)));

#define NB 8
#define LQ 3072
#define CC 768
#define NHEADS 6
#define NPTS 4
#define DHEAD 128
#define HLVL 64
#define WLVL 64
#define LIN 4096
#define HID 192
#define BLTOT 24576   // NB*LQ
#define FROWS 32768   // NB*LIN

// ---------------- LayerNorm (f32 in) -> bf16 out, C=768, 256 thr/row ----------------
__global__ __launch_bounds__(256)
void ln_bf16_kernel(const float* __restrict__ x, const float* __restrict__ w,
                    const float* __restrict__ b, bf16* __restrict__ out)
{
    const int row = blockIdx.x;
    const int t = threadIdx.x;
    const float* xr = x + (size_t)row * CC;
    float v0 = xr[t], v1 = xr[t + 256], v2 = xr[t + 512];
    float s = v0 + v1 + v2;
    float ss = v0 * v0 + v1 * v1 + v2 * v2;
    #pragma unroll
    for (int o = 32; o > 0; o >>= 1) {
        s += __shfl_down(s, o);
        ss += __shfl_down(ss, o);
    }
    __shared__ float red[8];
    const int lane = t & 63, wv = t >> 6;
    if (lane == 0) { red[wv] = s; red[4 + wv] = ss; }
    __syncthreads();
    if (t == 0) {
        float S = red[0] + red[1] + red[2] + red[3];
        float SS = red[4] + red[5] + red[6] + red[7];
        float m = S * (1.f / CC);
        float var = SS * (1.f / CC) - m * m;
        red[0] = m; red[1] = rsqrtf(var + 1e-6f);
    }
    __syncthreads();
    const float m = red[0], rs = red[1];
    bf16* o = out + (size_t)row * CC;
    o[t]       = __float2bfloat16((v0 - m) * rs * w[t] + b[t]);
    o[t + 256] = __float2bfloat16((v1 - m) * rs * w[t + 256] + b[t + 256]);
    o[t + 512] = __float2bfloat16((v2 - m) * rs * w[t + 512] + b[t + 512]);
}

// ---------------- weight f32 (K,N) -> bf16 transposed (N,K) ----------------
__global__ __launch_bounds__(256)
void wt_bf16_kernel(const float* __restrict__ src, bf16* __restrict__ dst, int K, int N)
{
    int i = blockIdx.x * 256 + threadIdx.x;
    if (i < K * N) {
        int n = i / K, k = i - n * K;
        dst[i] = __float2bfloat16(src[(size_t)k * N + n]);
    }
}

// ---------------- combined sampling-offset/attn-weight projection, padded to N=128 ----------------
__global__ __launch_bounds__(256)
void build_dots_w(const float* __restrict__ so_w, const float* __restrict__ so_b,
                  const float* __restrict__ aw_w, const float* __restrict__ aw_b,
                  bf16* __restrict__ wt, float* __restrict__ db)
{
    int i = blockIdx.x * 256 + threadIdx.x;  // over 128*768
    if (i < 128 * 768) {
        int n = i / 768, k = i - n * 768;
        float v = 0.f;
        if (n < 48) v = so_w[(size_t)k * 48 + n];
        else if (n < 72) v = aw_w[(size_t)k * 24 + (n - 48)];
        wt[i] = __float2bfloat16(v);
    }
    if (i < 128) {
        float bv = 0.f;
        if (i < 48) bv = so_b[i];
        else if (i < 72) bv = aw_b[i - 48];
        db[i] = bv;
    }
}

// ---------------- bf16 MFMA GEMM: C = A(M,K) * Bt(N,K)^T + bias (+res) ----------------
// global_load_lds(16B) staging, linear LDS dest + inverse-swizzled source + swizzled ds_read
// MODE 0: bf16 out = acc+bias ; MODE 1: f32 out = acc+bias+res ; MODE 2: f32 out = acc+bias
template<int BM, int BN, int BK, int WM, int WN, int MODE>
__global__ __launch_bounds__(256)
void gemm_kernel(const bf16* __restrict__ A, const bf16* __restrict__ Bt,
                 const float* __restrict__ bias, const float* res,
                 void* outv, int M, int N, int K)
{
    static_assert(BK == 64, "staging math assumes BK=64 (128B rows, 8x16B slots)");
    constexpr int WAVES_N = BN / WN;
    constexpr int FM = WM / 16, FN = WN / 16;
    constexpr int CWA = BM / 32;                // wave-loads of A per wave (8 rows each)
    constexpr int CWB = BN / 32;
    __shared__ bf16 sA[BM * 64];
    __shared__ bf16 sB[BN * 64];
    const int tid = threadIdx.x;
    const int lane = tid & 63;
    const int wave = tid >> 6;

    // XCD-aware bijective block swizzle (all grids used are divisible by 8):
    // hardware bid%8 = XCD -> give each XCD a contiguous logical chunk so the
    // nwgx blocks sharing an A-panel stay in one XCD's L2.
    const int nwgx = gridDim.x;
    const int nwg = nwgx * gridDim.y;
    const int bid = blockIdx.y * nwgx + blockIdx.x;
    const int swz = (bid & 7) * (nwg >> 3) + (bid >> 3);
    const int m0 = (swz / nwgx) * BM;
    const int n0 = (swz % nwgx) * BN;

    const int wm = (wave / WAVES_N) * WM;
    const int wn = (wave % WAVES_N) * WN;

    const int srow = lane >> 3;                 // row within 8-row chunk
    const int scol = ((lane & 7) ^ srow) * 8;   // inverse-swizzled source slot (elements)

    f32x4 acc[FM][FN] = {};

    for (int k0 = 0; k0 < K; k0 += BK) {
        #pragma unroll
        for (int i = 0; i < CWA; ++i) {
            const int c = i * 4 + wave;         // 8-row chunk id, wave-uniform
            const int row = c * 8 + srow;
            __builtin_amdgcn_global_load_lds(
                (const __attribute__((address_space(1))) void*)(A + (size_t)(m0 + row) * K + k0 + scol),
                (__attribute__((address_space(3))) void*)(&sA[c * 512]), 16, 0, 0);
        }
        #pragma unroll
        for (int i = 0; i < CWB; ++i) {
            const int c = i * 4 + wave;
            const int row = c * 8 + srow;
            __builtin_amdgcn_global_load_lds(
                (const __attribute__((address_space(1))) void*)(Bt + (size_t)(n0 + row) * K + k0 + scol),
                (__attribute__((address_space(3))) void*)(&sB[c * 512]), 16, 0, 0);
        }
        __syncthreads();
        #pragma unroll
        for (int kki = 0; kki < 2; ++kki) {
            const int kslot = kki * 4 + (lane >> 4);    // logical 16B slot (k-octet)
            bf16x8 aF[FM], bF[FN];
            #pragma unroll
            for (int i = 0; i < FM; ++i) {
                const int row = wm + i * 16 + (lane & 15);
                aF[i] = *(const bf16x8*)(&sA[row * 64 + ((kslot ^ (row & 7)) * 8)]);
            }
            #pragma unroll
            for (int j = 0; j < FN; ++j) {
                const int row = wn + j * 16 + (lane & 15);
                bF[j] = *(const bf16x8*)(&sB[row * 64 + ((kslot ^ (row & 7)) * 8)]);
            }
            #pragma unroll
            for (int i = 0; i < FM; ++i) {
                #pragma unroll
                for (int j = 0; j < FN; ++j)
                    acc[i][j] = __builtin_amdgcn_mfma_f32_16x16x32_bf16(aF[i], bF[j], acc[i][j], 0, 0, 0);
            }
        }
        __syncthreads();
    }

    #pragma unroll
    for (int i = 0; i < FM; ++i) {
        #pragma unroll
        for (int j = 0; j < FN; ++j) {
            const int colg = n0 + wn + j * 16 + (lane & 15);
            #pragma unroll
            for (int r = 0; r < 4; ++r) {
                const int rowg = m0 + wm + i * 16 + ((lane >> 4) << 2) + r;
                float v = acc[i][j][r] + bias[colg];
                size_t idx = (size_t)rowg * N + colg;
                if constexpr (MODE == 0)      ((bf16*)outv)[idx] = __float2bfloat16(v);
                else if constexpr (MODE == 1) ((float*)outv)[idx] = v + res[idx];
                else                          ((float*)outv)[idx] = v;
            }
        }
    }
}

// ---------------- softmax over 4 pts + sampling locations ----------------
__global__ __launch_bounds__(256)
void locsoftmax_kernel(const float* __restrict__ dots, const float* __restrict__ refp,
                       float4* __restrict__ params)
{
    int i = blockIdx.x * 256 + threadIdx.x;
    if (i >= BLTOT * NHEADS) return;
    int bl = i / NHEADS, h = i - bl * NHEADS;
    const float* d = dots + (size_t)bl * 128;
    float rx = refp[(size_t)bl * 2], ry = refp[(size_t)bl * 2 + 1];
    float l0 = d[48 + h * 4 + 0], l1 = d[48 + h * 4 + 1];
    float l2 = d[48 + h * 4 + 2], l3 = d[48 + h * 4 + 3];
    float mx = fmaxf(fmaxf(l0, l1), fmaxf(l2, l3));
    float e0 = expf(l0 - mx), e1 = expf(l1 - mx), e2 = expf(l2 - mx), e3 = expf(l3 - mx);
    float inv = 1.f / (e0 + e1 + e2 + e3);
    float ee[4] = {e0, e1, e2, e3};
    #pragma unroll
    for (int p = 0; p < 4; ++p) {
        float ox = d[h * 8 + p * 2], oy = d[h * 8 + p * 2 + 1];
        params[(size_t)i * 4 + p] =
            make_float4(rx + ox * (1.f / WLVL), ry + oy * (1.f / HLVL), ee[p] * inv, 0.f);
    }
}

// ---------------- bilinear sample + attention-weighted sum (16 lanes x 8ch per q-head) ----------------
__global__ __launch_bounds__(256)
void sampler_kernel(const bf16* __restrict__ value, const float4* __restrict__ params,
                    bf16* __restrict__ attn_in)
{
    const int tid = threadIdx.x;
    const int g = blockIdx.x * 16 + (tid >> 4);     // query-head index = bl*NHEADS + h
    const int lane16 = tid & 15;
    const int bl = g / NHEADS;
    const int h = g - bl * NHEADS;
    const int b = bl / LQ;
    const int c = lane16 * 8;                       // 8 channels per lane
    const bf16* vh = value + (size_t)b * LIN * CC + h * DHEAD + c;

    float acc[8] = {};
    #pragma unroll
    for (int p = 0; p < NPTS; ++p) {
        float4 pr = params[(size_t)g * 4 + p];
        float x = pr.x * (float)WLVL - 0.5f;
        float y = pr.y * (float)HLVL - 0.5f;
        float x0f = floorf(x), y0f = floorf(y);
        float wx1 = x - x0f, wy1 = y - y0f;
        float wx0 = 1.f - wx1, wy0 = 1.f - wy1;
        int x0 = (int)x0f, y0 = (int)y0f;
        float aw = pr.z;
        #pragma unroll
        for (int dy = 0; dy < 2; ++dy) {
            int yi = y0 + dy;
            if (yi < 0 || yi >= HLVL) continue;
            float wy = dy ? wy1 : wy0;
            #pragma unroll
            for (int dx = 0; dx < 2; ++dx) {
                int xi = x0 + dx;
                if (xi < 0 || xi >= WLVL) continue;
                float wgt = aw * wy * (dx ? wx1 : wx0);
                bf16x8 v = *(const bf16x8*)(vh + (size_t)(yi * WLVL + xi) * CC);
                #pragma unroll
                for (int j = 0; j < 8; ++j)
                    acc[j] += wgt * __uint_as_float(((unsigned)(unsigned short)v[j]) << 16);
            }
        }
    }
    bf16 tmp[8];
    #pragma unroll
    for (int j = 0; j < 8; ++j) tmp[j] = __float2bfloat16(acc[j]);
    *(bf16x8*)(attn_in + (size_t)bl * CC + h * DHEAD + c) = *(bf16x8*)tmp;
}

// ---------------- depthwise 3x3 conv + bias + exact GELU ----------------
__global__ void dwconv_gelu_kernel(const float* __restrict__ z, const float* __restrict__ dw_w,
                                   const float* __restrict__ dw_b, bf16* __restrict__ g)
{
    const int m = blockIdx.x;                   // row in (B*Lq)
    const int c = threadIdx.x;                  // 192 channels
    const int pix = m & 1023;
    const int h = pix >> 5, w = pix & 31;
    float acc = dw_b[c];
    #pragma unroll
    for (int dy = -1; dy <= 1; ++dy) {
        int hh2 = h + dy;
        if (hh2 < 0 || hh2 >= 32) continue;
        #pragma unroll
        for (int dx = -1; dx <= 1; ++dx) {
            int ww2 = w + dx;
            if (ww2 < 0 || ww2 >= 32) continue;
            acc += z[(size_t)(m + dy * 32 + dx) * HID + c] * dw_w[c * 9 + (dy + 1) * 3 + (dx + 1)];
        }
    }
    float ge = acc * 0.5f * (1.f + erff(acc * 0.70710678118f));
    g[(size_t)m * HID + c] = __float2bfloat16(ge);
}

extern "C" void kernel_launch(void* const* d_in, const int* in_sizes, int n_in,
                              void* d_out, int out_size, void* d_ws, size_t ws_size,
                              hipStream_t stream)
{
    const float* query = (const float*)d_in[0];
    const float* refp  = (const float*)d_in[1];
    const float* feat  = (const float*)d_in[2];
    const float* qn_w = (const float*)d_in[7];
    const float* qn_b = (const float*)d_in[8];
    const float* fn_w = (const float*)d_in[9];
    const float* fn_b = (const float*)d_in[10];
    const float* so_w = (const float*)d_in[11];
    const float* so_b = (const float*)d_in[12];
    const float* aw_w = (const float*)d_in[13];
    const float* aw_b = (const float*)d_in[14];
    const float* vp_w = (const float*)d_in[15];
    const float* vp_b = (const float*)d_in[16];
    const float* op_w = (const float*)d_in[17];
    const float* op_b = (const float*)d_in[18];
    const float* ffn_w = (const float*)d_in[19];
    const float* ffn_b = (const float*)d_in[20];
    const float* fc1_w = (const float*)d_in[21];
    const float* fc1_b = (const float*)d_in[22];
    const float* dw_w = (const float*)d_in[23];
    const float* dw_b = (const float*)d_in[24];
    const float* fc2_w = (const float*)d_in[25];
    const float* fc2_b = (const float*)d_in[26];
    float* out = (float*)d_out;

    // ---- workspace layout (all 256B aligned) ----
    if (ws_size < (size_t)125829632) return;    // need ~126MB
    char* ws = (char*)d_ws;
    bf16* vp_wt   = (bf16*)(ws + 0);            // 768x768
    bf16* op_wt   = (bf16*)(ws + 1179648);      // 768x768
    bf16* fc1_wt  = (bf16*)(ws + 2359296);      // 192x768
    bf16* fc2_wt  = (bf16*)(ws + 2654208);      // 768x192
    bf16* dots_wt = (bf16*)(ws + 2949120);      // 128x768
    float* dots_b = (float*)(ws + 3145728);     // 128
    float4* params = (float4*)(ws + 3146240);   // 24576*24 float4
    float* dots_out = (float*)(ws + 12583424);  // 24576*128 f32
    char* regA = ws + 25166336;                 // 50.3MB: f_ln -> attn_in -> z
    char* regB = ws + 75497984;                 // 50.3MB: q_ln -> value -> y -> g
    bf16* f_ln    = (bf16*)regA;
    bf16* attn_in = (bf16*)regA;
    float* z      = (float*)regA;
    bf16* q_ln  = (bf16*)regB;
    bf16* value = (bf16*)regB;
    bf16* y     = (bf16*)regB;
    bf16* g     = (bf16*)regB;

    // ---- weight prep (bf16, transposed to (N,K)) ----
    wt_bf16_kernel<<<2304, 256, 0, stream>>>(vp_w, vp_wt, 768, 768);
    wt_bf16_kernel<<<2304, 256, 0, stream>>>(op_w, op_wt, 768, 768);
    wt_bf16_kernel<<<576, 256, 0, stream>>>(fc1_w, fc1_wt, 768, 192);
    wt_bf16_kernel<<<576, 256, 0, stream>>>(fc2_w, fc2_wt, 192, 768);
    build_dots_w<<<384, 256, 0, stream>>>(so_w, so_b, aw_w, aw_b, dots_wt, dots_b);

    // ---- MSDeformAttn ----
    ln_bf16_kernel<<<BLTOT, 256, 0, stream>>>(query, qn_w, qn_b, q_ln);
    gemm_kernel<128, 128, 64, 64, 64, 2><<<dim3(1, BLTOT / 128), 256, 0, stream>>>(
        q_ln, dots_wt, dots_b, nullptr, dots_out, BLTOT, 128, 768);
    locsoftmax_kernel<<<(BLTOT * NHEADS + 255) / 256, 256, 0, stream>>>(dots_out, refp, params);
    ln_bf16_kernel<<<FROWS, 256, 0, stream>>>(feat, fn_w, fn_b, f_ln);
    gemm_kernel<128, 128, 64, 64, 64, 0><<<dim3(6, FROWS / 128), 256, 0, stream>>>(
        f_ln, vp_wt, vp_b, nullptr, value, FROWS, 768, 768);
    sampler_kernel<<<(BLTOT * NHEADS) / 16, 256, 0, stream>>>(value, params, attn_in);
    gemm_kernel<128, 128, 64, 64, 64, 1><<<dim3(6, BLTOT / 128), 256, 0, stream>>>(
        attn_in, op_wt, op_b, query, out, BLTOT, 768, 768);

    // ---- ConvFFN ----
    ln_bf16_kernel<<<BLTOT, 256, 0, stream>>>(out, ffn_w, ffn_b, y);
    gemm_kernel<128, 64, 64, 32, 64, 2><<<dim3(3, BLTOT / 128), 256, 0, stream>>>(
        y, fc1_wt, fc1_b, nullptr, z, BLTOT, HID, 768);
    dwconv_gelu_kernel<<<BLTOT, HID, 0, stream>>>(z, dw_w, dw_b, g);
    gemm_kernel<128, 128, 64, 64, 64, 1><<<dim3(6, BLTOT / 128), 256, 0, stream>>>(
        g, fc2_wt, fc2_b, out, out, BLTOT, 768, HID);
}

// Round 4
// 376.424 us; speedup vs baseline: 1.8197x; 1.2792x over previous
//
#include <hip/hip_runtime.h>
#include <hip/hip_bf16.h>
#include <math.h>

typedef __hip_bfloat16 bf16;
typedef short bf16x8 __attribute__((ext_vector_type(8)));
typedef float f32x4 __attribute__((ext_vector_type(4)));

#define NB 8
#define LQ 3072
#define CC 768
#define NHEADS 6
#define NPTS 4
#define DHEAD 128
#define HLVL 64
#define WLVL 64
#define LIN 4096
#define HID 192
#define BLTOT 24576   // NB*LQ
#define FROWS 32768   // NB*LIN

// ---------------- LayerNorm (f32 in) -> bf16 out, C=768, 256 thr/row ----------------
__global__ __launch_bounds__(256)
void ln_bf16_kernel(const float* __restrict__ x, const float* __restrict__ w,
                    const float* __restrict__ b, bf16* __restrict__ out)
{
    const int row = blockIdx.x;
    const int t = threadIdx.x;
    const float* xr = x + (size_t)row * CC;
    float v0 = xr[t], v1 = xr[t + 256], v2 = xr[t + 512];
    float s = v0 + v1 + v2;
    float ss = v0 * v0 + v1 * v1 + v2 * v2;
    #pragma unroll
    for (int o = 32; o > 0; o >>= 1) {
        s += __shfl_down(s, o);
        ss += __shfl_down(ss, o);
    }
    __shared__ float red[8];
    const int lane = t & 63, wv = t >> 6;
    if (lane == 0) { red[wv] = s; red[4 + wv] = ss; }
    __syncthreads();
    if (t == 0) {
        float S = red[0] + red[1] + red[2] + red[3];
        float SS = red[4] + red[5] + red[6] + red[7];
        float m = S * (1.f / CC);
        float var = SS * (1.f / CC) - m * m;
        red[0] = m; red[1] = rsqrtf(var + 1e-6f);
    }
    __syncthreads();
    const float m = red[0], rs = red[1];
    bf16* o = out + (size_t)row * CC;
    o[t]       = __float2bfloat16((v0 - m) * rs * w[t] + b[t]);
    o[t + 256] = __float2bfloat16((v1 - m) * rs * w[t + 256] + b[t + 256]);
    o[t + 512] = __float2bfloat16((v2 - m) * rs * w[t + 512] + b[t + 512]);
}

// ---------------- weight f32 (K,N) -> bf16 transposed (N,K) ----------------
__global__ __launch_bounds__(256)
void wt_bf16_kernel(const float* __restrict__ src, bf16* __restrict__ dst, int K, int N)
{
    int i = blockIdx.x * 256 + threadIdx.x;
    if (i < K * N) {
        int n = i / K, k = i - n * K;
        dst[i] = __float2bfloat16(src[(size_t)k * N + n]);
    }
}

// ---------------- combined sampling-offset/attn-weight projection, padded to N=128 ----------------
__global__ __launch_bounds__(256)
void build_dots_w(const float* __restrict__ so_w, const float* __restrict__ so_b,
                  const float* __restrict__ aw_w, const float* __restrict__ aw_b,
                  bf16* __restrict__ wt, float* __restrict__ db)
{
    int i = blockIdx.x * 256 + threadIdx.x;  // over 128*768
    if (i < 128 * 768) {
        int n = i / 768, k = i - n * 768;
        float v = 0.f;
        if (n < 48) v = so_w[(size_t)k * 48 + n];
        else if (n < 72) v = aw_w[(size_t)k * 24 + (n - 48)];
        wt[i] = __float2bfloat16(v);
    }
    if (i < 128) {
        float bv = 0.f;
        if (i < 48) bv = so_b[i];
        else if (i < 72) bv = aw_b[i - 48];
        db[i] = bv;
    }
}

template<int N_>
__device__ __forceinline__ void wait_vmcnt()
{
    if constexpr (N_ == 0)      asm volatile("s_waitcnt vmcnt(0)" ::: "memory");
    else if constexpr (N_ == 6) asm volatile("s_waitcnt vmcnt(6)" ::: "memory");
    else if constexpr (N_ == 8) asm volatile("s_waitcnt vmcnt(8)" ::: "memory");
    else static_assert(N_ == 0 || N_ == 6 || N_ == 8, "add a vmcnt case");
}

// ---------------- bf16 MFMA GEMM: C = A(M,K) * Bt(N,K)^T + bias (+res) ----------------
// 2-deep pipelined global_load_lds staging (counted vmcnt, raw barriers),
// XOR-swizzled LDS, LDS-transpose epilogue with float4/bf16x8 stores.
// MODE 0: bf16 out ; MODE 1: f32 out = acc+bias+res ; MODE 2: f32 out = acc+bias
template<int BM, int BN, int WM, int WN, int MODE>
__global__ __launch_bounds__(256)
void gemm_kernel(const bf16* __restrict__ A, const bf16* __restrict__ Bt,
                 const float* __restrict__ bias, const float* __restrict__ res,
                 void* __restrict__ outv, int M, int N, int K)
{
    constexpr int WAVES_N = BN / WN;
    constexpr int FM = WM / 16, FN = WN / 16;
    constexpr int CWA = BM / 32;                // wave-loads of A per wave per tile
    constexpr int CWB = BN / 32;
    constexpr int LPT = CWA + CWB;              // gload_lds per wave per K-tile
    constexpr int ABYTES = BM * 256;            // 2 halves of A tile (bytes)
    constexpr int DBUF_BYTES = (BM + BN) * 256;
    constexpr int EPI_BYTES = BM * BN * 4;
    constexpr size_t SMEM_BYTES = DBUF_BYTES > EPI_BYTES ? DBUF_BYTES : EPI_BYTES;
    __shared__ __align__(16) char smem[SMEM_BYTES];
    bf16* sA = (bf16*)smem;
    bf16* sB = (bf16*)(smem + ABYTES);
    float* epi = (float*)smem;

    const int tid = threadIdx.x;
    const int lane = tid & 63;
    const int wave = tid >> 6;

    // XCD-aware bijective block swizzle (all grids divisible by 8)
    const int nwgx = gridDim.x;
    const int nwg = nwgx * gridDim.y;
    const int bid = blockIdx.y * nwgx + blockIdx.x;
    const int swz = (bid & 7) * (nwg >> 3) + (bid >> 3);
    const int m0 = (swz / nwgx) * BM;
    const int n0 = (swz % nwgx) * BN;

    const int wm = (wave / WAVES_N) * WM;
    const int wn = (wave % WAVES_N) * WN;

    const int srow = lane >> 3;                 // row within 8-row chunk
    const int scol = ((lane & 7) ^ srow) * 8;   // inverse-swizzled source slot (elements)

#define STAGE(tt, half)                                                                            \
    { const int k0_ = (tt) * 64;                                                                   \
      _Pragma("unroll")                                                                            \
      for (int i_ = 0; i_ < CWA; ++i_) {                                                           \
        const int c_ = i_ * 4 + wave;                                                              \
        __builtin_amdgcn_global_load_lds(                                                          \
          (const __attribute__((address_space(1))) void*)(A + (size_t)(m0 + c_ * 8 + srow) * K + k0_ + scol), \
          (__attribute__((address_space(3))) void*)(sA + (half) * (BM * 64) + c_ * 512), 16, 0, 0); } \
      _Pragma("unroll")                                                                            \
      for (int i_ = 0; i_ < CWB; ++i_) {                                                           \
        const int c_ = i_ * 4 + wave;                                                              \
        __builtin_amdgcn_global_load_lds(                                                          \
          (const __attribute__((address_space(1))) void*)(Bt + (size_t)(n0 + c_ * 8 + srow) * K + k0_ + scol), \
          (__attribute__((address_space(3))) void*)(sB + (half) * (BN * 64) + c_ * 512), 16, 0, 0); } }

    f32x4 acc[FM][FN] = {};
    const int nt = K >> 6;

    STAGE(0, 0);
    STAGE(1, 1);

    for (int t = 0; t < nt; ++t) {
        const int half = t & 1;
        if (t + 1 < nt) wait_vmcnt<LPT>();      // my tile-t loads done; t+1 stays in flight
        else            wait_vmcnt<0>();
        __builtin_amdgcn_s_barrier();           // all waves' tile-t chunks resident
        const bf16* cA = sA + half * (BM * 64);
        const bf16* cB = sB + half * (BN * 64);
        #pragma unroll
        for (int kki = 0; kki < 2; ++kki) {
            const int kslot = kki * 4 + (lane >> 4);
            bf16x8 aF[FM], bF[FN];
            #pragma unroll
            for (int i = 0; i < FM; ++i) {
                const int row = wm + i * 16 + (lane & 15);
                aF[i] = *(const bf16x8*)(&cA[row * 64 + ((kslot ^ (row & 7)) * 8)]);
            }
            #pragma unroll
            for (int j = 0; j < FN; ++j) {
                const int row = wn + j * 16 + (lane & 15);
                bF[j] = *(const bf16x8*)(&cB[row * 64 + ((kslot ^ (row & 7)) * 8)]);
            }
            #pragma unroll
            for (int i = 0; i < FM; ++i) {
                #pragma unroll
                for (int j = 0; j < FN; ++j)
                    acc[i][j] = __builtin_amdgcn_mfma_f32_16x16x32_bf16(aF[i], bF[j], acc[i][j], 0, 0, 0);
            }
        }
        asm volatile("s_waitcnt lgkmcnt(0)" ::: "memory");
        __builtin_amdgcn_s_barrier();           // all waves done reading buf[half]
        if (t + 2 < nt) STAGE(t + 2, half);     // safe to overwrite
    }
#undef STAGE

    // ---- epilogue: acc -> LDS (group-XOR swizzle) -> vectorized global ----
    #pragma unroll
    for (int j = 0; j < FN; ++j) {
        const int colL = wn + j * 16 + (lane & 15);
        const float bj = bias[n0 + colL];
        #pragma unroll
        for (int i = 0; i < FM; ++i) {
            #pragma unroll
            for (int r = 0; r < 4; ++r) {
                const int rowL = wm + i * 16 + ((lane >> 4) << 2) + r;
                const int addr = rowL * BN + ((((colL >> 2) ^ (rowL & 7)) << 2) | (colL & 3));
                epi[addr] = acc[i][j][r] + bj;
            }
        }
    }
    __syncthreads();

    if constexpr (MODE == 0) {
        constexpr int GPR = BN / 8;
        constexpr int GPT = (BM * BN / 8) / 256;
        #pragma unroll
        for (int k = 0; k < GPT; ++k) {
            const int f = k * 256 + tid;
            const int rr = f / GPR, cc = (f % GPR) * 8;
            const int g0 = ((cc >> 2) ^ (rr & 7)) << 2;
            const int g1 = (((cc >> 2) + 1) ^ (rr & 7)) << 2;
            float4 v0 = *(const float4*)&epi[rr * BN + g0];
            float4 v1 = *(const float4*)&epi[rr * BN + g1];
            bf16 tmp[8];
            tmp[0] = __float2bfloat16(v0.x); tmp[1] = __float2bfloat16(v0.y);
            tmp[2] = __float2bfloat16(v0.z); tmp[3] = __float2bfloat16(v0.w);
            tmp[4] = __float2bfloat16(v1.x); tmp[5] = __float2bfloat16(v1.y);
            tmp[6] = __float2bfloat16(v1.z); tmp[7] = __float2bfloat16(v1.w);
            *(bf16x8*)((bf16*)outv + (size_t)(m0 + rr) * N + n0 + cc) = *(bf16x8*)tmp;
        }
    } else {
        constexpr int QPR = BN / 4;
        constexpr int QPT = (BM * BN / 4) / 256;
        #pragma unroll
        for (int k = 0; k < QPT; ++k) {
            const int f = k * 256 + tid;
            const int rr = f / QPR, cc = (f % QPR) * 4;
            const int gs = ((cc >> 2) ^ (rr & 7)) << 2;
            float4 v = *(const float4*)&epi[rr * BN + gs];
            const size_t gidx = (size_t)(m0 + rr) * N + n0 + cc;
            if constexpr (MODE == 1) {
                float4 q = *(const float4*)&res[gidx];
                v.x += q.x; v.y += q.y; v.z += q.z; v.w += q.w;
            }
            *(float4*)&((float*)outv)[gidx] = v;
        }
    }
}

// ---------------- softmax over 4 pts + sampling locations ----------------
__global__ __launch_bounds__(256)
void locsoftmax_kernel(const float* __restrict__ dots, const float* __restrict__ refp,
                       float4* __restrict__ params)
{
    int i = blockIdx.x * 256 + threadIdx.x;
    if (i >= BLTOT * NHEADS) return;
    int bl = i / NHEADS, h = i - bl * NHEADS;
    const float* d = dots + (size_t)bl * 128;
    float rx = refp[(size_t)bl * 2], ry = refp[(size_t)bl * 2 + 1];
    float l0 = d[48 + h * 4 + 0], l1 = d[48 + h * 4 + 1];
    float l2 = d[48 + h * 4 + 2], l3 = d[48 + h * 4 + 3];
    float mx = fmaxf(fmaxf(l0, l1), fmaxf(l2, l3));
    float e0 = expf(l0 - mx), e1 = expf(l1 - mx), e2 = expf(l2 - mx), e3 = expf(l3 - mx);
    float inv = 1.f / (e0 + e1 + e2 + e3);
    float ee[4] = {e0, e1, e2, e3};
    #pragma unroll
    for (int p = 0; p < 4; ++p) {
        float ox = d[h * 8 + p * 2], oy = d[h * 8 + p * 2 + 1];
        params[(size_t)i * 4 + p] =
            make_float4(rx + ox * (1.f / WLVL), ry + oy * (1.f / HLVL), ee[p] * inv, 0.f);
    }
}

// ---------------- bilinear sample + attention-weighted sum (16 lanes x 8ch per q-head) ----------------
__global__ __launch_bounds__(256)
void sampler_kernel(const bf16* __restrict__ value, const float4* __restrict__ params,
                    bf16* __restrict__ attn_in)
{
    const int tid = threadIdx.x;
    const int g = blockIdx.x * 16 + (tid >> 4);     // query-head index = bl*NHEADS + h
    const int lane16 = tid & 15;
    const int bl = g / NHEADS;
    const int h = g - bl * NHEADS;
    const int b = bl / LQ;
    const int c = lane16 * 8;                       // 8 channels per lane
    const bf16* vh = value + (size_t)b * LIN * CC + h * DHEAD + c;

    float acc[8] = {};
    #pragma unroll
    for (int p = 0; p < NPTS; ++p) {
        float4 pr = params[(size_t)g * 4 + p];
        float x = pr.x * (float)WLVL - 0.5f;
        float y = pr.y * (float)HLVL - 0.5f;
        float x0f = floorf(x), y0f = floorf(y);
        float wx1 = x - x0f, wy1 = y - y0f;
        float wx0 = 1.f - wx1, wy0 = 1.f - wy1;
        int x0 = (int)x0f, y0 = (int)y0f;
        float aw = pr.z;
        #pragma unroll
        for (int dy = 0; dy < 2; ++dy) {
            int yi = y0 + dy;
            if (yi < 0 || yi >= HLVL) continue;
            float wy = dy ? wy1 : wy0;
            #pragma unroll
            for (int dx = 0; dx < 2; ++dx) {
                int xi = x0 + dx;
                if (xi < 0 || xi >= WLVL) continue;
                float wgt = aw * wy * (dx ? wx1 : wx0);
                bf16x8 v = *(const bf16x8*)(vh + (size_t)(yi * WLVL + xi) * CC);
                #pragma unroll
                for (int j = 0; j < 8; ++j)
                    acc[j] += wgt * __uint_as_float(((unsigned)(unsigned short)v[j]) << 16);
            }
        }
    }
    bf16 tmp[8];
    #pragma unroll
    for (int j = 0; j < 8; ++j) tmp[j] = __float2bfloat16(acc[j]);
    *(bf16x8*)(attn_in + (size_t)bl * CC + h * DHEAD + c) = *(bf16x8*)tmp;
}

// ---------------- depthwise 3x3 conv + bias + exact GELU ----------------
__global__ void dwconv_gelu_kernel(const float* __restrict__ z, const float* __restrict__ dw_w,
                                   const float* __restrict__ dw_b, bf16* __restrict__ g)
{
    const int m = blockIdx.x;                   // row in (B*Lq)
    const int c = threadIdx.x;                  // 192 channels
    const int pix = m & 1023;
    const int h = pix >> 5, w = pix & 31;
    float acc = dw_b[c];
    #pragma unroll
    for (int dy = -1; dy <= 1; ++dy) {
        int hh2 = h + dy;
        if (hh2 < 0 || hh2 >= 32) continue;
        #pragma unroll
        for (int dx = -1; dx <= 1; ++dx) {
            int ww2 = w + dx;
            if (ww2 < 0 || ww2 >= 32) continue;
            acc += z[(size_t)(m + dy * 32 + dx) * HID + c] * dw_w[c * 9 + (dy + 1) * 3 + (dx + 1)];
        }
    }
    float ge = acc * 0.5f * (1.f + erff(acc * 0.70710678118f));
    g[(size_t)m * HID + c] = __float2bfloat16(ge);
}

extern "C" void kernel_launch(void* const* d_in, const int* in_sizes, int n_in,
                              void* d_out, int out_size, void* d_ws, size_t ws_size,
                              hipStream_t stream)
{
    const float* query = (const float*)d_in[0];
    const float* refp  = (const float*)d_in[1];
    const float* feat  = (const float*)d_in[2];
    const float* qn_w = (const float*)d_in[7];
    const float* qn_b = (const float*)d_in[8];
    const float* fn_w = (const float*)d_in[9];
    const float* fn_b = (const float*)d_in[10];
    const float* so_w = (const float*)d_in[11];
    const float* so_b = (const float*)d_in[12];
    const float* aw_w = (const float*)d_in[13];
    const float* aw_b = (const float*)d_in[14];
    const float* vp_w = (const float*)d_in[15];
    const float* vp_b = (const float*)d_in[16];
    const float* op_w = (const float*)d_in[17];
    const float* op_b = (const float*)d_in[18];
    const float* ffn_w = (const float*)d_in[19];
    const float* ffn_b = (const float*)d_in[20];
    const float* fc1_w = (const float*)d_in[21];
    const float* fc1_b = (const float*)d_in[22];
    const float* dw_w = (const float*)d_in[23];
    const float* dw_b = (const float*)d_in[24];
    const float* fc2_w = (const float*)d_in[25];
    const float* fc2_b = (const float*)d_in[26];
    float* out = (float*)d_out;

    // ---- workspace layout (all 256B aligned) ----
    if (ws_size < (size_t)125829632) return;    // need ~126MB
    char* ws = (char*)d_ws;
    bf16* vp_wt   = (bf16*)(ws + 0);            // 768x768
    bf16* op_wt   = (bf16*)(ws + 1179648);      // 768x768
    bf16* fc1_wt  = (bf16*)(ws + 2359296);      // 192x768
    bf16* fc2_wt  = (bf16*)(ws + 2654208);      // 768x192
    bf16* dots_wt = (bf16*)(ws + 2949120);      // 128x768
    float* dots_b = (float*)(ws + 3145728);     // 128
    float4* params = (float4*)(ws + 3146240);   // 24576*24 float4
    float* dots_out = (float*)(ws + 12583424);  // 24576*128 f32
    char* regA = ws + 25166336;                 // 50.3MB: f_ln -> attn_in -> z
    char* regB = ws + 75497984;                 // 50.3MB: q_ln -> value -> y -> g
    bf16* f_ln    = (bf16*)regA;
    bf16* attn_in = (bf16*)regA;
    float* z      = (float*)regA;
    bf16* q_ln  = (bf16*)regB;
    bf16* value = (bf16*)regB;
    bf16* y     = (bf16*)regB;
    bf16* g     = (bf16*)regB;

    // ---- weight prep (bf16, transposed to (N,K)) ----
    wt_bf16_kernel<<<2304, 256, 0, stream>>>(vp_w, vp_wt, 768, 768);
    wt_bf16_kernel<<<2304, 256, 0, stream>>>(op_w, op_wt, 768, 768);
    wt_bf16_kernel<<<576, 256, 0, stream>>>(fc1_w, fc1_wt, 768, 192);
    wt_bf16_kernel<<<576, 256, 0, stream>>>(fc2_w, fc2_wt, 192, 768);
    build_dots_w<<<384, 256, 0, stream>>>(so_w, so_b, aw_w, aw_b, dots_wt, dots_b);

    // ---- MSDeformAttn ----
    ln_bf16_kernel<<<BLTOT, 256, 0, stream>>>(query, qn_w, qn_b, q_ln);
    gemm_kernel<128, 128, 64, 64, 2><<<dim3(1, BLTOT / 128), 256, 0, stream>>>(
        q_ln, dots_wt, dots_b, nullptr, dots_out, BLTOT, 128, 768);
    locsoftmax_kernel<<<(BLTOT * NHEADS + 255) / 256, 256, 0, stream>>>(dots_out, refp, params);
    ln_bf16_kernel<<<FROWS, 256, 0, stream>>>(feat, fn_w, fn_b, f_ln);
    gemm_kernel<128, 128, 64, 64, 0><<<dim3(6, FROWS / 128), 256, 0, stream>>>(
        f_ln, vp_wt, vp_b, nullptr, value, FROWS, 768, 768);
    sampler_kernel<<<(BLTOT * NHEADS) / 16, 256, 0, stream>>>(value, params, attn_in);
    gemm_kernel<128, 128, 64, 64, 1><<<dim3(6, BLTOT / 128), 256, 0, stream>>>(
        attn_in, op_wt, op_b, query, out, BLTOT, 768, 768);

    // ---- ConvFFN ----
    ln_bf16_kernel<<<BLTOT, 256, 0, stream>>>(out, ffn_w, ffn_b, y);
    gemm_kernel<128, 64, 32, 64, 2><<<dim3(3, BLTOT / 128), 256, 0, stream>>>(
        y, fc1_wt, fc1_b, nullptr, z, BLTOT, HID, 768);
    dwconv_gelu_kernel<<<BLTOT, HID, 0, stream>>>(z, dw_w, dw_b, g);
    gemm_kernel<128, 128, 64, 64, 1><<<dim3(6, BLTOT / 128), 256, 0, stream>>>(
        g, fc2_wt, fc2_b, out, out, BLTOT, 768, HID);
}

// Round 5
// 347.574 us; speedup vs baseline: 1.9707x; 1.0830x over previous
//
#include <hip/hip_runtime.h>
#include <hip/hip_bf16.h>
#include <math.h>

typedef __hip_bfloat16 bf16;
typedef short bf16x8 __attribute__((ext_vector_type(8)));
typedef float f32x4 __attribute__((ext_vector_type(4)));

#define NB 8
#define LQ 3072
#define CC 768
#define NHEADS 6
#define NPTS 4
#define DHEAD 128
#define HLVL 64
#define WLVL 64
#define LIN 4096
#define HID 192
#define BLTOT 24576   // NB*LQ
#define FROWS 32768   // NB*LIN

// ---------------- LayerNorm (f32 in) -> bf16 out, C=768, 256 thr/row ----------------
__global__ __launch_bounds__(256)
void ln_bf16_kernel(const float* __restrict__ x, const float* __restrict__ w,
                    const float* __restrict__ b, bf16* __restrict__ out)
{
    const int row = blockIdx.x;
    const int t = threadIdx.x;
    const float* xr = x + (size_t)row * CC;
    float v0 = xr[t], v1 = xr[t + 256], v2 = xr[t + 512];
    float s = v0 + v1 + v2;
    float ss = v0 * v0 + v1 * v1 + v2 * v2;
    #pragma unroll
    for (int o = 32; o > 0; o >>= 1) {
        s += __shfl_down(s, o);
        ss += __shfl_down(ss, o);
    }
    __shared__ float red[8];
    const int lane = t & 63, wv = t >> 6;
    if (lane == 0) { red[wv] = s; red[4 + wv] = ss; }
    __syncthreads();
    if (t == 0) {
        float S = red[0] + red[1] + red[2] + red[3];
        float SS = red[4] + red[5] + red[6] + red[7];
        float m = S * (1.f / CC);
        float var = SS * (1.f / CC) - m * m;
        red[0] = m; red[1] = rsqrtf(var + 1e-6f);
    }
    __syncthreads();
    const float m = red[0], rs = red[1];
    bf16* o = out + (size_t)row * CC;
    o[t]       = __float2bfloat16((v0 - m) * rs * w[t] + b[t]);
    o[t + 256] = __float2bfloat16((v1 - m) * rs * w[t + 256] + b[t + 256]);
    o[t + 512] = __float2bfloat16((v2 - m) * rs * w[t + 512] + b[t + 512]);
}

// ---------------- weight f32 (K,N) -> bf16 transposed (N,K), 64x64 LDS tiles ----------------
__global__ __launch_bounds__(256)
void wt_bf16_kernel(const float* __restrict__ src, bf16* __restrict__ dst, int K, int N)
{
    __shared__ float t[64][65];
    const int tn0 = blockIdx.x * 64, tk0 = blockIdx.y * 64;
    const int r = threadIdx.x >> 6, c = threadIdx.x & 63;
    #pragma unroll
    for (int i = 0; i < 16; ++i) {
        const int k = i * 4 + r;
        t[k][c] = src[(size_t)(tk0 + k) * N + tn0 + c];
    }
    __syncthreads();
    #pragma unroll
    for (int i = 0; i < 16; ++i) {
        const int n = i * 4 + r;
        dst[(size_t)(tn0 + n) * K + tk0 + c] = __float2bfloat16(t[c][n]);
    }
}

// ---------------- combined sampling-offset/attn-weight projection, padded to N=128 ----------------
__global__ __launch_bounds__(256)
void build_dots_w(const float* __restrict__ so_w, const float* __restrict__ so_b,
                  const float* __restrict__ aw_w, const float* __restrict__ aw_b,
                  bf16* __restrict__ wt, float* __restrict__ db)
{
    int i = blockIdx.x * 256 + threadIdx.x;  // over 128*768
    if (i < 128 * 768) {
        int n = i / 768, k = i - n * 768;
        float v = 0.f;
        if (n < 48) v = so_w[(size_t)k * 48 + n];
        else if (n < 72) v = aw_w[(size_t)k * 24 + (n - 48)];
        wt[i] = __float2bfloat16(v);
    }
    if (i < 128) {
        float bv = 0.f;
        if (i < 48) bv = so_b[i];
        else if (i < 72) bv = aw_b[i - 48];
        db[i] = bv;
    }
}

template<int N_>
__device__ __forceinline__ void wait_vmcnt()
{
    if constexpr (N_ == 0)      asm volatile("s_waitcnt vmcnt(0)" ::: "memory");
    else if constexpr (N_ == 4) asm volatile("s_waitcnt vmcnt(4)" ::: "memory");
    else if constexpr (N_ == 6) asm volatile("s_waitcnt vmcnt(6)" ::: "memory");
    else if constexpr (N_ == 8) asm volatile("s_waitcnt vmcnt(8)" ::: "memory");
    else static_assert(N_ == 0 || N_ == 4 || N_ == 6 || N_ == 8, "add a vmcnt case");
}

// ---------------- bf16 MFMA GEMM: C = A(M,K) * Bt(N,K)^T + bias (+res) ----------------
// 2-deep pipelined global_load_lds staging (counted vmcnt, raw barriers),
// XOR-swizzled LDS, LDS-transpose epilogue with float4/bf16x8 stores.
// MODE 0: bf16 out ; MODE 1: f32 out = acc+bias+res ; MODE 2: f32 out = acc+bias
template<int BM, int BN, int WM, int WN, int MODE>
__global__ __launch_bounds__(256)
void gemm_kernel(const bf16* __restrict__ A, const bf16* __restrict__ Bt,
                 const float* __restrict__ bias, const float* __restrict__ res,
                 void* __restrict__ outv, int M, int N, int K)
{
    constexpr int WAVES_N = BN / WN;
    constexpr int FM = WM / 16, FN = WN / 16;
    constexpr int CWA = BM / 32;                // wave-loads of A per wave per tile
    constexpr int CWB = BN / 32;
    constexpr int LPT = CWA + CWB;              // gload_lds per wave per K-tile
    constexpr int ABYTES = BM * 256;            // 2 halves of A tile (bytes)
    constexpr int DBUF_BYTES = (BM + BN) * 256;
    constexpr int EPI_BYTES = BM * BN * 4;
    constexpr size_t SMEM_BYTES = DBUF_BYTES > EPI_BYTES ? DBUF_BYTES : EPI_BYTES;
    __shared__ __align__(16) char smem[SMEM_BYTES];
    bf16* sA = (bf16*)smem;
    bf16* sB = (bf16*)(smem + ABYTES);
    float* epi = (float*)smem;

    const int tid = threadIdx.x;
    const int lane = tid & 63;
    const int wave = tid >> 6;

    // XCD-aware bijective block swizzle (all grids divisible by 8)
    const int nwgx = gridDim.x;
    const int nwg = nwgx * gridDim.y;
    const int bid = blockIdx.y * nwgx + blockIdx.x;
    const int swz = (bid & 7) * (nwg >> 3) + (bid >> 3);
    const int m0 = (swz / nwgx) * BM;
    const int n0 = (swz % nwgx) * BN;

    const int wm = (wave / WAVES_N) * WM;
    const int wn = (wave % WAVES_N) * WN;

    const int srow = lane >> 3;                 // row within 8-row chunk
    const int scol = ((lane & 7) ^ srow) * 8;   // inverse-swizzled source slot (elements)

#define STAGE(tt, half)                                                                            \
    { const int k0_ = (tt) * 64;                                                                   \
      _Pragma("unroll")                                                                            \
      for (int i_ = 0; i_ < CWA; ++i_) {                                                           \
        const int c_ = i_ * 4 + wave;                                                              \
        __builtin_amdgcn_global_load_lds(                                                          \
          (const __attribute__((address_space(1))) void*)(A + (size_t)(m0 + c_ * 8 + srow) * K + k0_ + scol), \
          (__attribute__((address_space(3))) void*)(sA + (half) * (BM * 64) + c_ * 512), 16, 0, 0); } \
      _Pragma("unroll")                                                                            \
      for (int i_ = 0; i_ < CWB; ++i_) {                                                           \
        const int c_ = i_ * 4 + wave;                                                              \
        __builtin_amdgcn_global_load_lds(                                                          \
          (const __attribute__((address_space(1))) void*)(Bt + (size_t)(n0 + c_ * 8 + srow) * K + k0_ + scol), \
          (__attribute__((address_space(3))) void*)(sB + (half) * (BN * 64) + c_ * 512), 16, 0, 0); } }

    f32x4 acc[FM][FN] = {};
    const int nt = K >> 6;

    STAGE(0, 0);
    STAGE(1, 1);

    for (int t = 0; t < nt; ++t) {
        const int half = t & 1;
        if (t + 1 < nt) wait_vmcnt<LPT>();      // my tile-t loads done; t+1 stays in flight
        else            wait_vmcnt<0>();
        __builtin_amdgcn_s_barrier();           // all waves' tile-t chunks resident
        const bf16* cA = sA + half * (BM * 64);
        const bf16* cB = sB + half * (BN * 64);
        #pragma unroll
        for (int kki = 0; kki < 2; ++kki) {
            const int kslot = kki * 4 + (lane >> 4);
            bf16x8 aF[FM], bF[FN];
            #pragma unroll
            for (int i = 0; i < FM; ++i) {
                const int row = wm + i * 16 + (lane & 15);
                aF[i] = *(const bf16x8*)(&cA[row * 64 + ((kslot ^ (row & 7)) * 8)]);
            }
            #pragma unroll
            for (int j = 0; j < FN; ++j) {
                const int row = wn + j * 16 + (lane & 15);
                bF[j] = *(const bf16x8*)(&cB[row * 64 + ((kslot ^ (row & 7)) * 8)]);
            }
            #pragma unroll
            for (int i = 0; i < FM; ++i) {
                #pragma unroll
                for (int j = 0; j < FN; ++j)
                    acc[i][j] = __builtin_amdgcn_mfma_f32_16x16x32_bf16(aF[i], bF[j], acc[i][j], 0, 0, 0);
            }
        }
        asm volatile("s_waitcnt lgkmcnt(0)" ::: "memory");
        __builtin_amdgcn_s_barrier();           // all waves done reading buf[half]
        if (t + 2 < nt) STAGE(t + 2, half);     // safe to overwrite
    }
#undef STAGE

    // ---- epilogue: acc -> LDS (group-XOR swizzle) -> vectorized global ----
    #pragma unroll
    for (int j = 0; j < FN; ++j) {
        const int colL = wn + j * 16 + (lane & 15);
        const float bj = bias[n0 + colL];
        #pragma unroll
        for (int i = 0; i < FM; ++i) {
            #pragma unroll
            for (int r = 0; r < 4; ++r) {
                const int rowL = wm + i * 16 + ((lane >> 4) << 2) + r;
                const int addr = rowL * BN + ((((colL >> 2) ^ (rowL & 7)) << 2) | (colL & 3));
                epi[addr] = acc[i][j][r] + bj;
            }
        }
    }
    __syncthreads();

    if constexpr (MODE == 0) {
        constexpr int GPR = BN / 8;
        constexpr int GPT = (BM * BN / 8) / 256;
        #pragma unroll
        for (int k = 0; k < GPT; ++k) {
            const int f = k * 256 + tid;
            const int rr = f / GPR, cc = (f % GPR) * 8;
            const int g0 = ((cc >> 2) ^ (rr & 7)) << 2;
            const int g1 = (((cc >> 2) + 1) ^ (rr & 7)) << 2;
            float4 v0 = *(const float4*)&epi[rr * BN + g0];
            float4 v1 = *(const float4*)&epi[rr * BN + g1];
            bf16 tmp[8];
            tmp[0] = __float2bfloat16(v0.x); tmp[1] = __float2bfloat16(v0.y);
            tmp[2] = __float2bfloat16(v0.z); tmp[3] = __float2bfloat16(v0.w);
            tmp[4] = __float2bfloat16(v1.x); tmp[5] = __float2bfloat16(v1.y);
            tmp[6] = __float2bfloat16(v1.z); tmp[7] = __float2bfloat16(v1.w);
            *(bf16x8*)((bf16*)outv + (size_t)(m0 + rr) * N + n0 + cc) = *(bf16x8*)tmp;
        }
    } else {
        constexpr int QPR = BN / 4;
        constexpr int QPT = (BM * BN / 4) / 256;
        #pragma unroll
        for (int k = 0; k < QPT; ++k) {
            const int f = k * 256 + tid;
            const int rr = f / QPR, cc = (f % QPR) * 4;
            const int gs = ((cc >> 2) ^ (rr & 7)) << 2;
            float4 v = *(const float4*)&epi[rr * BN + gs];
            const size_t gidx = (size_t)(m0 + rr) * N + n0 + cc;
            if constexpr (MODE == 1) {
                float4 q = *(const float4*)&res[gidx];
                v.x += q.x; v.y += q.y; v.z += q.z; v.w += q.w;
            }
            *(float4*)&((float*)outv)[gidx] = v;
        }
    }
}

// ---------------- softmax over 4 pts + sampling locations ----------------
__global__ __launch_bounds__(256)
void locsoftmax_kernel(const float* __restrict__ dots, const float* __restrict__ refp,
                       float4* __restrict__ params)
{
    int i = blockIdx.x * 256 + threadIdx.x;
    if (i >= BLTOT * NHEADS) return;
    int bl = i / NHEADS, h = i - bl * NHEADS;
    const float* d = dots + (size_t)bl * 128;
    float rx = refp[(size_t)bl * 2], ry = refp[(size_t)bl * 2 + 1];
    float l0 = d[48 + h * 4 + 0], l1 = d[48 + h * 4 + 1];
    float l2 = d[48 + h * 4 + 2], l3 = d[48 + h * 4 + 3];
    float mx = fmaxf(fmaxf(l0, l1), fmaxf(l2, l3));
    float e0 = expf(l0 - mx), e1 = expf(l1 - mx), e2 = expf(l2 - mx), e3 = expf(l3 - mx);
    float inv = 1.f / (e0 + e1 + e2 + e3);
    float ee[4] = {e0, e1, e2, e3};
    #pragma unroll
    for (int p = 0; p < 4; ++p) {
        float ox = d[h * 8 + p * 2], oy = d[h * 8 + p * 2 + 1];
        params[(size_t)i * 4 + p] =
            make_float4(rx + ox * (1.f / WLVL), ry + oy * (1.f / HLVL), ee[p] * inv, 0.f);
    }
}

// ---------------- bilinear sample: branchless, 16 loads in flight (16 lanes x 8ch per q-head) --------
__global__ __launch_bounds__(256)
void sampler_kernel(const bf16* __restrict__ value, const float4* __restrict__ params,
                    bf16* __restrict__ attn_in)
{
    const int tid = threadIdx.x;
    const int g = blockIdx.x * 16 + (tid >> 4);     // query-head index = bl*NHEADS + h
    const int lane16 = tid & 15;
    const int bl = g / NHEADS;
    const int h = g - bl * NHEADS;
    const int b = bl / LQ;
    const bf16* vh = value + (size_t)b * LIN * CC + h * DHEAD + lane16 * 8;

    int offs[16];
    float wgt[16];
    #pragma unroll
    for (int p = 0; p < NPTS; ++p) {
        float4 pr = params[(size_t)g * 4 + p];
        float x = pr.x * (float)WLVL - 0.5f;
        float y = pr.y * (float)HLVL - 0.5f;
        float x0f = floorf(x), y0f = floorf(y);
        float wx1 = x - x0f, wy1 = y - y0f;
        float wx0 = 1.f - wx1, wy0 = 1.f - wy1;
        int x0 = (int)x0f, y0 = (int)y0f;
        #pragma unroll
        for (int dy = 0; dy < 2; ++dy) {
            const int yi = y0 + dy;
            const int yc = min(max(yi, 0), HLVL - 1);
            const float wy = (dy ? wy1 : wy0) * ((yi >= 0 && yi < HLVL) ? pr.z : 0.f);
            #pragma unroll
            for (int dx = 0; dx < 2; ++dx) {
                const int xi = x0 + dx;
                const int xc = min(max(xi, 0), WLVL - 1);
                const int idx = p * 4 + dy * 2 + dx;
                offs[idx] = (yc * WLVL + xc) * CC;
                wgt[idx] = wy * (dx ? wx1 : wx0) * ((xi >= 0 && xi < WLVL) ? 1.f : 0.f);
            }
        }
    }
    bf16x8 v[16];
    #pragma unroll
    for (int i = 0; i < 16; ++i) v[i] = *(const bf16x8*)(vh + offs[i]);
    float acc[8] = {};
    #pragma unroll
    for (int i = 0; i < 16; ++i) {
        #pragma unroll
        for (int j = 0; j < 8; ++j)
            acc[j] += wgt[i] * __uint_as_float(((unsigned)(unsigned short)v[i][j]) << 16);
    }
    bf16 tmp[8];
    #pragma unroll
    for (int j = 0; j < 8; ++j) tmp[j] = __float2bfloat16(acc[j]);
    *(bf16x8*)(attn_in + (size_t)bl * CC + h * DHEAD + lane16 * 8) = *(bf16x8*)tmp;
}

// ---------------- depthwise 3x3 conv + bias + exact GELU ----------------
__global__ void dwconv_gelu_kernel(const float* __restrict__ z, const float* __restrict__ dw_w,
                                   const float* __restrict__ dw_b, bf16* __restrict__ g)
{
    const int m = blockIdx.x;                   // row in (B*Lq)
    const int c = threadIdx.x;                  // 192 channels
    const int pix = m & 1023;
    const int h = pix >> 5, w = pix & 31;
    float acc = dw_b[c];
    #pragma unroll
    for (int dy = -1; dy <= 1; ++dy) {
        int hh2 = h + dy;
        if (hh2 < 0 || hh2 >= 32) continue;
        #pragma unroll
        for (int dx = -1; dx <= 1; ++dx) {
            int ww2 = w + dx;
            if (ww2 < 0 || ww2 >= 32) continue;
            acc += z[(size_t)(m + dy * 32 + dx) * HID + c] * dw_w[c * 9 + (dy + 1) * 3 + (dx + 1)];
        }
    }
    float ge = acc * 0.5f * (1.f + erff(acc * 0.70710678118f));
    g[(size_t)m * HID + c] = __float2bfloat16(ge);
}

extern "C" void kernel_launch(void* const* d_in, const int* in_sizes, int n_in,
                              void* d_out, int out_size, void* d_ws, size_t ws_size,
                              hipStream_t stream)
{
    const float* query = (const float*)d_in[0];
    const float* refp  = (const float*)d_in[1];
    const float* feat  = (const float*)d_in[2];
    const float* qn_w = (const float*)d_in[7];
    const float* qn_b = (const float*)d_in[8];
    const float* fn_w = (const float*)d_in[9];
    const float* fn_b = (const float*)d_in[10];
    const float* so_w = (const float*)d_in[11];
    const float* so_b = (const float*)d_in[12];
    const float* aw_w = (const float*)d_in[13];
    const float* aw_b = (const float*)d_in[14];
    const float* vp_w = (const float*)d_in[15];
    const float* vp_b = (const float*)d_in[16];
    const float* op_w = (const float*)d_in[17];
    const float* op_b = (const float*)d_in[18];
    const float* ffn_w = (const float*)d_in[19];
    const float* ffn_b = (const float*)d_in[20];
    const float* fc1_w = (const float*)d_in[21];
    const float* fc1_b = (const float*)d_in[22];
    const float* dw_w = (const float*)d_in[23];
    const float* dw_b = (const float*)d_in[24];
    const float* fc2_w = (const float*)d_in[25];
    const float* fc2_b = (const float*)d_in[26];
    float* out = (float*)d_out;

    // ---- workspace layout (all 256B aligned) ----
    if (ws_size < (size_t)125829632) return;    // need ~126MB
    char* ws = (char*)d_ws;
    bf16* vp_wt   = (bf16*)(ws + 0);            // 768x768
    bf16* op_wt   = (bf16*)(ws + 1179648);      // 768x768
    bf16* fc1_wt  = (bf16*)(ws + 2359296);      // 192x768
    bf16* fc2_wt  = (bf16*)(ws + 2654208);      // 768x192
    bf16* dots_wt = (bf16*)(ws + 2949120);      // 128x768
    float* dots_b = (float*)(ws + 3145728);     // 128
    float4* params = (float4*)(ws + 3146240);   // 24576*24 float4
    float* dots_out = (float*)(ws + 12583424);  // 24576*128 f32
    char* regA = ws + 25166336;                 // 50.3MB: f_ln -> attn_in -> z
    char* regB = ws + 75497984;                 // 50.3MB: q_ln -> value -> y -> g
    bf16* f_ln    = (bf16*)regA;
    bf16* attn_in = (bf16*)regA;
    float* z      = (float*)regA;
    bf16* q_ln  = (bf16*)regB;
    bf16* value = (bf16*)regB;
    bf16* y     = (bf16*)regB;
    bf16* g     = (bf16*)regB;

    // ---- weight prep (bf16, transposed to (N,K)) ----
    wt_bf16_kernel<<<dim3(12, 12), 256, 0, stream>>>(vp_w, vp_wt, 768, 768);
    wt_bf16_kernel<<<dim3(12, 12), 256, 0, stream>>>(op_w, op_wt, 768, 768);
    wt_bf16_kernel<<<dim3(3, 12), 256, 0, stream>>>(fc1_w, fc1_wt, 768, 192);
    wt_bf16_kernel<<<dim3(12, 3), 256, 0, stream>>>(fc2_w, fc2_wt, 192, 768);
    build_dots_w<<<384, 256, 0, stream>>>(so_w, so_b, aw_w, aw_b, dots_wt, dots_b);

    // ---- MSDeformAttn ----
    ln_bf16_kernel<<<BLTOT, 256, 0, stream>>>(query, qn_w, qn_b, q_ln);
    gemm_kernel<64, 128, 32, 64, 2><<<dim3(1, BLTOT / 64), 256, 0, stream>>>(
        q_ln, dots_wt, dots_b, nullptr, dots_out, BLTOT, 128, 768);
    locsoftmax_kernel<<<(BLTOT * NHEADS + 255) / 256, 256, 0, stream>>>(dots_out, refp, params);
    ln_bf16_kernel<<<FROWS, 256, 0, stream>>>(feat, fn_w, fn_b, f_ln);
    gemm_kernel<128, 128, 64, 64, 0><<<dim3(6, FROWS / 128), 256, 0, stream>>>(
        f_ln, vp_wt, vp_b, nullptr, value, FROWS, 768, 768);
    sampler_kernel<<<(BLTOT * NHEADS) / 16, 256, 0, stream>>>(value, params, attn_in);
    gemm_kernel<64, 128, 32, 64, 1><<<dim3(6, BLTOT / 64), 256, 0, stream>>>(
        attn_in, op_wt, op_b, query, out, BLTOT, 768, 768);

    // ---- ConvFFN ----
    ln_bf16_kernel<<<BLTOT, 256, 0, stream>>>(out, ffn_w, ffn_b, y);
    gemm_kernel<64, 64, 16, 64, 2><<<dim3(3, BLTOT / 64), 256, 0, stream>>>(
        y, fc1_wt, fc1_b, nullptr, z, BLTOT, HID, 768);
    dwconv_gelu_kernel<<<BLTOT, HID, 0, stream>>>(z, dw_w, dw_b, g);
    gemm_kernel<64, 128, 32, 64, 1><<<dim3(6, BLTOT / 64), 256, 0, stream>>>(
        g, fc2_wt, fc2_b, out, out, BLTOT, 768, HID);
}

// Round 6
// 342.943 us; speedup vs baseline: 1.9973x; 1.0135x over previous
//
#include <hip/hip_runtime.h>
#include <hip/hip_bf16.h>
#include <math.h>

typedef __hip_bfloat16 bf16;
typedef short bf16x8 __attribute__((ext_vector_type(8)));
typedef short bf16x4 __attribute__((ext_vector_type(4)));
typedef float f32x4 __attribute__((ext_vector_type(4)));

#define NB 8
#define LQ 3072
#define CC 768
#define NHEADS 6
#define NPTS 4
#define DHEAD 128
#define HLVL 64
#define WLVL 64
#define LIN 4096
#define HID 192
#define BLTOT 24576   // NB*LQ
#define FROWS 32768   // NB*LIN

__device__ __forceinline__ float bf2f(short u)
{ return __uint_as_float(((unsigned)(unsigned short)u) << 16); }

// ---------------- LayerNorm (f32 in) -> bf16 out, C=768, 256 thr/row ----------------
__global__ __launch_bounds__(256)
void ln_bf16_kernel(const float* __restrict__ x, const float* __restrict__ w,
                    const float* __restrict__ b, bf16* __restrict__ out)
{
    const int row = blockIdx.x;
    const int t = threadIdx.x;
    const float* xr = x + (size_t)row * CC;
    float v0 = xr[t], v1 = xr[t + 256], v2 = xr[t + 512];
    float s = v0 + v1 + v2;
    float ss = v0 * v0 + v1 * v1 + v2 * v2;
    #pragma unroll
    for (int o = 32; o > 0; o >>= 1) {
        s += __shfl_down(s, o);
        ss += __shfl_down(ss, o);
    }
    __shared__ float red[8];
    const int lane = t & 63, wv = t >> 6;
    if (lane == 0) { red[wv] = s; red[4 + wv] = ss; }
    __syncthreads();
    if (t == 0) {
        float S = red[0] + red[1] + red[2] + red[3];
        float SS = red[4] + red[5] + red[6] + red[7];
        float m = S * (1.f / CC);
        float var = SS * (1.f / CC) - m * m;
        red[0] = m; red[1] = rsqrtf(var + 1e-6f);
    }
    __syncthreads();
    const float m = red[0], rs = red[1];
    bf16* o = out + (size_t)row * CC;
    o[t]       = __float2bfloat16((v0 - m) * rs * w[t] + b[t]);
    o[t + 256] = __float2bfloat16((v1 - m) * rs * w[t + 256] + b[t + 256]);
    o[t + 512] = __float2bfloat16((v2 - m) * rs * w[t + 512] + b[t + 512]);
}

// ---------------- LayerNorm (bf16 in) -> bf16 out, one wave per row, no barriers ----------------
__global__ __launch_bounds__(256)
void ln_bf16in_kernel(const bf16* __restrict__ x, const float* __restrict__ w,
                      const float* __restrict__ b, bf16* __restrict__ out)
{
    const int row = blockIdx.x * 4 + (threadIdx.x >> 6);
    const int lane = threadIdx.x & 63;
    const bf16* xr = x + (size_t)row * CC;
    bf16x8 v8 = *(const bf16x8*)(xr + lane * 8);
    bf16x4 v4 = *(const bf16x4*)(xr + 512 + lane * 4);
    float v[12];
    #pragma unroll
    for (int j = 0; j < 8; ++j) v[j] = bf2f(v8[j]);
    #pragma unroll
    for (int j = 0; j < 4; ++j) v[8 + j] = bf2f(v4[j]);
    float s = 0.f, ss = 0.f;
    #pragma unroll
    for (int j = 0; j < 12; ++j) { s += v[j]; ss += v[j] * v[j]; }
    #pragma unroll
    for (int o = 32; o > 0; o >>= 1) {
        s += __shfl_down(s, o);
        ss += __shfl_down(ss, o);
    }
    s = __shfl(s, 0); ss = __shfl(ss, 0);
    const float m = s * (1.f / CC);
    const float rs = rsqrtf(ss * (1.f / CC) - m * m + 1e-6f);
    float wv[12], bv[12];
    *(float4*)&wv[0] = *(const float4*)&w[lane * 8];
    *(float4*)&wv[4] = *(const float4*)&w[lane * 8 + 4];
    *(float4*)&wv[8] = *(const float4*)&w[512 + lane * 4];
    *(float4*)&bv[0] = *(const float4*)&b[lane * 8];
    *(float4*)&bv[4] = *(const float4*)&b[lane * 8 + 4];
    *(float4*)&bv[8] = *(const float4*)&b[512 + lane * 4];
    bf16 o8[8], o4[4];
    #pragma unroll
    for (int j = 0; j < 8; ++j) o8[j] = __float2bfloat16((v[j] - m) * rs * wv[j] + bv[j]);
    #pragma unroll
    for (int j = 0; j < 4; ++j) o4[j] = __float2bfloat16((v[8 + j] - m) * rs * wv[8 + j] + bv[8 + j]);
    bf16* orow = out + (size_t)row * CC;
    *(bf16x8*)(orow + lane * 8) = *(bf16x8*)o8;
    *(bf16x4*)(orow + 512 + lane * 4) = *(bf16x4*)o4;
}

// ---------------- weight f32 (K,N) -> bf16 transposed (N,K), 64x64 LDS tiles ----------------
__global__ __launch_bounds__(256)
void wt_bf16_kernel(const float* __restrict__ src, bf16* __restrict__ dst, int K, int N)
{
    __shared__ float t[64][65];
    const int tn0 = blockIdx.x * 64, tk0 = blockIdx.y * 64;
    const int r = threadIdx.x >> 6, c = threadIdx.x & 63;
    #pragma unroll
    for (int i = 0; i < 16; ++i) {
        const int k = i * 4 + r;
        t[k][c] = src[(size_t)(tk0 + k) * N + tn0 + c];
    }
    __syncthreads();
    #pragma unroll
    for (int i = 0; i < 16; ++i) {
        const int n = i * 4 + r;
        dst[(size_t)(tn0 + n) * K + tk0 + c] = __float2bfloat16(t[c][n]);
    }
}

// ---------------- combined sampling-offset/attn-weight projection, padded to N=128 ----------------
__global__ __launch_bounds__(256)
void build_dots_w(const float* __restrict__ so_w, const float* __restrict__ so_b,
                  const float* __restrict__ aw_w, const float* __restrict__ aw_b,
                  bf16* __restrict__ wt, float* __restrict__ db)
{
    int i = blockIdx.x * 256 + threadIdx.x;  // over 128*768
    if (i < 128 * 768) {
        int n = i / 768, k = i - n * 768;
        float v = 0.f;
        if (n < 48) v = so_w[(size_t)k * 48 + n];
        else if (n < 72) v = aw_w[(size_t)k * 24 + (n - 48)];
        wt[i] = __float2bfloat16(v);
    }
    if (i < 128) {
        float bv = 0.f;
        if (i < 48) bv = so_b[i];
        else if (i < 72) bv = aw_b[i - 48];
        db[i] = bv;
    }
}

template<int N_>
__device__ __forceinline__ void wait_vmcnt()
{
    if constexpr (N_ == 0)      asm volatile("s_waitcnt vmcnt(0)" ::: "memory");
    else if constexpr (N_ == 4) asm volatile("s_waitcnt vmcnt(4)" ::: "memory");
    else if constexpr (N_ == 5) asm volatile("s_waitcnt vmcnt(5)" ::: "memory");
    else if constexpr (N_ == 6) asm volatile("s_waitcnt vmcnt(6)" ::: "memory");
    else if constexpr (N_ == 8) asm volatile("s_waitcnt vmcnt(8)" ::: "memory");
    else static_assert(N_ == 0, "add a vmcnt case");
}

// ---------------- bf16 MFMA GEMM: C = A(M,K) * Bt(N,K)^T + bias (+res) ----------------
// 2-deep pipelined global_load_lds staging (counted vmcnt, raw barriers),
// XOR-swizzled LDS, register-prefetched residual, LDS-transpose vectorized epilogue.
// MODE 0: bf16 out = acc+bias
// MODE 2: f32  out = acc+bias
// MODE 3: bf16 out = acc+bias+res_f32   (res prefetched to regs)
// MODE 4: f32  out = acc+bias+res_bf16  (res prefetched to regs)
template<int BM, int BN, int WM, int WN, int MODE>
__global__ __launch_bounds__(256)
void gemm_kernel(const bf16* __restrict__ A, const bf16* __restrict__ Bt,
                 const float* __restrict__ bias, const void* __restrict__ resv,
                 void* __restrict__ outv, int M, int N, int K)
{
    constexpr int WAVES_N = BN / WN;
    constexpr int FM = WM / 16, FN = WN / 16;
    constexpr int CWA = BM / 32;                // wave-loads of A per wave per tile
    constexpr int CWB = BN / 32;
    constexpr int LPT = CWA + CWB;              // gload_lds per wave per K-tile
    constexpr int ABYTES = BM * 256;            // 2 halves of A tile (bytes)
    constexpr int DBUF_BYTES = (BM + BN) * 256;
    constexpr int EPI_BYTES = BM * BN * 4;
    constexpr size_t SMEM_BYTES = DBUF_BYTES > EPI_BYTES ? DBUF_BYTES : EPI_BYTES;
    __shared__ __align__(16) char smem[SMEM_BYTES];
    bf16* sA = (bf16*)smem;
    bf16* sB = (bf16*)(smem + ABYTES);
    float* epi = (float*)smem;

    const int tid = threadIdx.x;
    const int lane = tid & 63;
    const int wave = tid >> 6;

    // XCD-aware bijective block swizzle (all grids divisible by 8)
    const int nwgx = gridDim.x;
    const int nwg = nwgx * gridDim.y;
    const int bid = blockIdx.y * nwgx + blockIdx.x;
    const int swz = (bid & 7) * (nwg >> 3) + (bid >> 3);
    const int m0 = (swz / nwgx) * BM;
    const int n0 = (swz % nwgx) * BN;

    const int wm = (wave / WAVES_N) * WM;
    const int wn = (wave % WAVES_N) * WN;

    const int srow = lane >> 3;                 // row within 8-row chunk
    const int scol = ((lane & 7) ^ srow) * 8;   // inverse-swizzled source slot (elements)

    // ---- residual prefetch into registers (overlaps the K-loop) ----
    constexpr int GPR8 = BN / 8;
    constexpr int GPT8 = (BM * BN / 8) / 256;
    constexpr int QPR4 = BN / 4;
    constexpr int QPT4 = (BM * BN / 4) / 256;
    float4 pr0[GPT8], pr1[GPT8];
    bf16x4 prb[QPT4];
    if constexpr (MODE == 3) {
        const float* resf = (const float*)resv;
        #pragma unroll
        for (int k = 0; k < GPT8; ++k) {
            const int f = k * 256 + tid;
            const int rr = f / GPR8, cc = (f % GPR8) * 8;
            const size_t gidx = (size_t)(m0 + rr) * N + n0 + cc;
            pr0[k] = *(const float4*)&resf[gidx];
            pr1[k] = *(const float4*)&resf[gidx + 4];
        }
    }
    if constexpr (MODE == 4) {
        const bf16* resb = (const bf16*)resv;
        #pragma unroll
        for (int k = 0; k < QPT4; ++k) {
            const int f = k * 256 + tid;
            const int rr = f / QPR4, cc = (f % QPR4) * 4;
            prb[k] = *(const bf16x4*)&resb[(size_t)(m0 + rr) * N + n0 + cc];
        }
    }

#define STAGE(tt, half)                                                                            \
    { const int k0_ = (tt) * 64;                                                                   \
      _Pragma("unroll")                                                                            \
      for (int i_ = 0; i_ < CWA; ++i_) {                                                           \
        const int c_ = i_ * 4 + wave;                                                              \
        __builtin_amdgcn_global_load_lds(                                                          \
          (const __attribute__((address_space(1))) void*)(A + (size_t)(m0 + c_ * 8 + srow) * K + k0_ + scol), \
          (__attribute__((address_space(3))) void*)(sA + (half) * (BM * 64) + c_ * 512), 16, 0, 0); } \
      _Pragma("unroll")                                                                            \
      for (int i_ = 0; i_ < CWB; ++i_) {                                                           \
        const int c_ = i_ * 4 + wave;                                                              \
        __builtin_amdgcn_global_load_lds(                                                          \
          (const __attribute__((address_space(1))) void*)(Bt + (size_t)(n0 + c_ * 8 + srow) * K + k0_ + scol), \
          (__attribute__((address_space(3))) void*)(sB + (half) * (BN * 64) + c_ * 512), 16, 0, 0); } }

    f32x4 acc[FM][FN] = {};
    const int nt = K >> 6;

    STAGE(0, 0);
    STAGE(1, 1);

    for (int t = 0; t < nt; ++t) {
        const int half = t & 1;
        if (t + 1 < nt) wait_vmcnt<LPT>();      // my tile-t loads done; t+1 (and any prefetch) handled by count
        else            wait_vmcnt<0>();
        __builtin_amdgcn_s_barrier();           // all waves' tile-t chunks resident
        const bf16* cA = sA + half * (BM * 64);
        const bf16* cB = sB + half * (BN * 64);
        #pragma unroll
        for (int kki = 0; kki < 2; ++kki) {
            const int kslot = kki * 4 + (lane >> 4);
            bf16x8 aF[FM], bF[FN];
            #pragma unroll
            for (int i = 0; i < FM; ++i) {
                const int row = wm + i * 16 + (lane & 15);
                aF[i] = *(const bf16x8*)(&cA[row * 64 + ((kslot ^ (row & 7)) * 8)]);
            }
            #pragma unroll
            for (int j = 0; j < FN; ++j) {
                const int row = wn + j * 16 + (lane & 15);
                bF[j] = *(const bf16x8*)(&cB[row * 64 + ((kslot ^ (row & 7)) * 8)]);
            }
            #pragma unroll
            for (int i = 0; i < FM; ++i) {
                #pragma unroll
                for (int j = 0; j < FN; ++j)
                    acc[i][j] = __builtin_amdgcn_mfma_f32_16x16x32_bf16(aF[i], bF[j], acc[i][j], 0, 0, 0);
            }
        }
        asm volatile("s_waitcnt lgkmcnt(0)" ::: "memory");
        __builtin_amdgcn_s_barrier();           // all waves done reading buf[half]
        if (t + 2 < nt) STAGE(t + 2, half);     // safe to overwrite
    }
#undef STAGE

    // ---- epilogue: acc -> LDS (group-XOR swizzle) -> vectorized global ----
    #pragma unroll
    for (int j = 0; j < FN; ++j) {
        const int colL = wn + j * 16 + (lane & 15);
        const float bj = bias[n0 + colL];
        #pragma unroll
        for (int i = 0; i < FM; ++i) {
            #pragma unroll
            for (int r = 0; r < 4; ++r) {
                const int rowL = wm + i * 16 + ((lane >> 4) << 2) + r;
                const int addr = rowL * BN + ((((colL >> 2) ^ (rowL & 7)) << 2) | (colL & 3));
                epi[addr] = acc[i][j][r] + bj;
            }
        }
    }
    __syncthreads();

    if constexpr (MODE == 0 || MODE == 3) {
        #pragma unroll
        for (int k = 0; k < GPT8; ++k) {
            const int f = k * 256 + tid;
            const int rr = f / GPR8, cc = (f % GPR8) * 8;
            const int g0 = ((cc >> 2) ^ (rr & 7)) << 2;
            const int g1 = (((cc >> 2) + 1) ^ (rr & 7)) << 2;
            float4 v0 = *(const float4*)&epi[rr * BN + g0];
            float4 v1 = *(const float4*)&epi[rr * BN + g1];
            if constexpr (MODE == 3) {
                v0.x += pr0[k].x; v0.y += pr0[k].y; v0.z += pr0[k].z; v0.w += pr0[k].w;
                v1.x += pr1[k].x; v1.y += pr1[k].y; v1.z += pr1[k].z; v1.w += pr1[k].w;
            }
            bf16 tmp[8];
            tmp[0] = __float2bfloat16(v0.x); tmp[1] = __float2bfloat16(v0.y);
            tmp[2] = __float2bfloat16(v0.z); tmp[3] = __float2bfloat16(v0.w);
            tmp[4] = __float2bfloat16(v1.x); tmp[5] = __float2bfloat16(v1.y);
            tmp[6] = __float2bfloat16(v1.z); tmp[7] = __float2bfloat16(v1.w);
            *(bf16x8*)((bf16*)outv + (size_t)(m0 + rr) * N + n0 + cc) = *(bf16x8*)tmp;
        }
    } else {
        #pragma unroll
        for (int k = 0; k < QPT4; ++k) {
            const int f = k * 256 + tid;
            const int rr = f / QPR4, cc = (f % QPR4) * 4;
            const int gs = ((cc >> 2) ^ (rr & 7)) << 2;
            float4 v = *(const float4*)&epi[rr * BN + gs];
            if constexpr (MODE == 4) {
                v.x += bf2f(prb[k][0]); v.y += bf2f(prb[k][1]);
                v.z += bf2f(prb[k][2]); v.w += bf2f(prb[k][3]);
            }
            *(float4*)&((float*)outv)[(size_t)(m0 + rr) * N + n0 + cc] = v;
        }
    }
}

// ---------------- softmax over 4 pts + sampling locations ----------------
__global__ __launch_bounds__(256)
void locsoftmax_kernel(const float* __restrict__ dots, const float* __restrict__ refp,
                       float4* __restrict__ params)
{
    int i = blockIdx.x * 256 + threadIdx.x;
    if (i >= BLTOT * NHEADS) return;
    int bl = i / NHEADS, h = i - bl * NHEADS;
    const float* d = dots + (size_t)bl * 128;
    float rx = refp[(size_t)bl * 2], ry = refp[(size_t)bl * 2 + 1];
    float l0 = d[48 + h * 4 + 0], l1 = d[48 + h * 4 + 1];
    float l2 = d[48 + h * 4 + 2], l3 = d[48 + h * 4 + 3];
    float mx = fmaxf(fmaxf(l0, l1), fmaxf(l2, l3));
    float e0 = expf(l0 - mx), e1 = expf(l1 - mx), e2 = expf(l2 - mx), e3 = expf(l3 - mx);
    float inv = 1.f / (e0 + e1 + e2 + e3);
    float ee[4] = {e0, e1, e2, e3};
    #pragma unroll
    for (int p = 0; p < 4; ++p) {
        float ox = d[h * 8 + p * 2], oy = d[h * 8 + p * 2 + 1];
        params[(size_t)i * 4 + p] =
            make_float4(rx + ox * (1.f / WLVL), ry + oy * (1.f / HLVL), ee[p] * inv, 0.f);
    }
}

// ---------------- bilinear sample: branchless, 16 loads in flight (16 lanes x 8ch per q-head) --------
__global__ __launch_bounds__(256)
void sampler_kernel(const bf16* __restrict__ value, const float4* __restrict__ params,
                    bf16* __restrict__ attn_in)
{
    const int tid = threadIdx.x;
    const int g = blockIdx.x * 16 + (tid >> 4);     // query-head index = bl*NHEADS + h
    const int lane16 = tid & 15;
    const int bl = g / NHEADS;
    const int h = g - bl * NHEADS;
    const int b = bl / LQ;
    const bf16* vh = value + (size_t)b * LIN * CC + h * DHEAD + lane16 * 8;

    int offs[16];
    float wgt[16];
    #pragma unroll
    for (int p = 0; p < NPTS; ++p) {
        float4 pr = params[(size_t)g * 4 + p];
        float x = pr.x * (float)WLVL - 0.5f;
        float y = pr.y * (float)HLVL - 0.5f;
        float x0f = floorf(x), y0f = floorf(y);
        float wx1 = x - x0f, wy1 = y - y0f;
        float wx0 = 1.f - wx1, wy0 = 1.f - wy1;
        int x0 = (int)x0f, y0 = (int)y0f;
        #pragma unroll
        for (int dy = 0; dy < 2; ++dy) {
            const int yi = y0 + dy;
            const int yc = min(max(yi, 0), HLVL - 1);
            const float wy = (dy ? wy1 : wy0) * ((yi >= 0 && yi < HLVL) ? pr.z : 0.f);
            #pragma unroll
            for (int dx = 0; dx < 2; ++dx) {
                const int xi = x0 + dx;
                const int xc = min(max(xi, 0), WLVL - 1);
                const int idx = p * 4 + dy * 2 + dx;
                offs[idx] = (yc * WLVL + xc) * CC;
                wgt[idx] = wy * (dx ? wx1 : wx0) * ((xi >= 0 && xi < WLVL) ? 1.f : 0.f);
            }
        }
    }
    bf16x8 v[16];
    #pragma unroll
    for (int i = 0; i < 16; ++i) v[i] = *(const bf16x8*)(vh + offs[i]);
    float acc[8] = {};
    #pragma unroll
    for (int i = 0; i < 16; ++i) {
        #pragma unroll
        for (int j = 0; j < 8; ++j)
            acc[j] += wgt[i] * bf2f(v[i][j]);
    }
    bf16 tmp[8];
    #pragma unroll
    for (int j = 0; j < 8; ++j) tmp[j] = __float2bfloat16(acc[j]);
    *(bf16x8*)(attn_in + (size_t)bl * CC + h * DHEAD + lane16 * 8) = *(bf16x8*)tmp;
}

// ---------------- depthwise 3x3 conv + bias + exact GELU (bf16 in/out, 4ch/thread) ----------------
__global__ __launch_bounds__(192)
void dwconv_gelu_kernel(const bf16* __restrict__ z, const float* __restrict__ dw_w,
                        const float* __restrict__ dw_b, bf16* __restrict__ g)
{
    const int tp = threadIdx.x / 48;            // pixel within block (4)
    const int tc = threadIdx.x % 48;            // channel group
    const int m = blockIdx.x * 4 + tp;
    const int c = tc * 4;
    const int pix = m & 1023;
    const int h = pix >> 5, w = pix & 31;
    float acc[4];
    #pragma unroll
    for (int j = 0; j < 4; ++j) acc[j] = dw_b[c + j];
    #pragma unroll
    for (int dy = -1; dy <= 1; ++dy) {
        int hh2 = h + dy;
        if (hh2 < 0 || hh2 >= 32) continue;
        #pragma unroll
        for (int dx = -1; dx <= 1; ++dx) {
            int ww2 = w + dx;
            if (ww2 < 0 || ww2 >= 32) continue;
            bf16x4 vv = *(const bf16x4*)&z[(size_t)(m + dy * 32 + dx) * HID + c];
            #pragma unroll
            for (int j = 0; j < 4; ++j)
                acc[j] += bf2f(vv[j]) * dw_w[(c + j) * 9 + (dy + 1) * 3 + (dx + 1)];
        }
    }
    bf16 tmp[4];
    #pragma unroll
    for (int j = 0; j < 4; ++j) {
        float ge = acc[j] * 0.5f * (1.f + erff(acc[j] * 0.70710678118f));
        tmp[j] = __float2bfloat16(ge);
    }
    *(bf16x4*)&g[(size_t)m * HID + c] = *(bf16x4*)tmp;
}

extern "C" void kernel_launch(void* const* d_in, const int* in_sizes, int n_in,
                              void* d_out, int out_size, void* d_ws, size_t ws_size,
                              hipStream_t stream)
{
    const float* query = (const float*)d_in[0];
    const float* refp  = (const float*)d_in[1];
    const float* feat  = (const float*)d_in[2];
    const float* qn_w = (const float*)d_in[7];
    const float* qn_b = (const float*)d_in[8];
    const float* fn_w = (const float*)d_in[9];
    const float* fn_b = (const float*)d_in[10];
    const float* so_w = (const float*)d_in[11];
    const float* so_b = (const float*)d_in[12];
    const float* aw_w = (const float*)d_in[13];
    const float* aw_b = (const float*)d_in[14];
    const float* vp_w = (const float*)d_in[15];
    const float* vp_b = (const float*)d_in[16];
    const float* op_w = (const float*)d_in[17];
    const float* op_b = (const float*)d_in[18];
    const float* ffn_w = (const float*)d_in[19];
    const float* ffn_b = (const float*)d_in[20];
    const float* fc1_w = (const float*)d_in[21];
    const float* fc1_b = (const float*)d_in[22];
    const float* dw_w = (const float*)d_in[23];
    const float* dw_b = (const float*)d_in[24];
    const float* fc2_w = (const float*)d_in[25];
    const float* fc2_b = (const float*)d_in[26];
    float* out = (float*)d_out;

    // ---- workspace layout (all 256B aligned) ----
    if (ws_size < (size_t)125829632) return;    // need ~126MB
    char* ws = (char*)d_ws;
    bf16* vp_wt   = (bf16*)(ws + 0);            // 768x768
    bf16* op_wt   = (bf16*)(ws + 1179648);      // 768x768
    bf16* fc1_wt  = (bf16*)(ws + 2359296);      // 192x768
    bf16* fc2_wt  = (bf16*)(ws + 2654208);      // 768x192
    bf16* dots_wt = (bf16*)(ws + 2949120);      // 128x768
    float* dots_b = (float*)(ws + 3145728);     // 128
    char* paramsR = ws + 3146240;               // 9.4MB: params -> g
    char* dotsR   = ws + 12583424;              // 12.6MB: dots_out -> z
    char* regA = ws + 25166336;                 // 50.3MB: f_ln -> attn_in -> y
    char* regB = ws + 75497984;                 // 50.3MB: q_ln -> value -> s_bf
    float4* params = (float4*)paramsR;
    bf16* g        = (bf16*)paramsR;
    float* dots_out = (float*)dotsR;
    bf16* z         = (bf16*)dotsR;
    bf16* f_ln    = (bf16*)regA;
    bf16* attn_in = (bf16*)regA;
    bf16* y       = (bf16*)regA;
    bf16* q_ln  = (bf16*)regB;
    bf16* value = (bf16*)regB;
    bf16* s_bf  = (bf16*)regB;

    // ---- weight prep (bf16, transposed to (N,K)) ----
    wt_bf16_kernel<<<dim3(12, 12), 256, 0, stream>>>(vp_w, vp_wt, 768, 768);
    wt_bf16_kernel<<<dim3(12, 12), 256, 0, stream>>>(op_w, op_wt, 768, 768);
    wt_bf16_kernel<<<dim3(3, 12), 256, 0, stream>>>(fc1_w, fc1_wt, 768, 192);
    wt_bf16_kernel<<<dim3(12, 3), 256, 0, stream>>>(fc2_w, fc2_wt, 192, 768);
    build_dots_w<<<384, 256, 0, stream>>>(so_w, so_b, aw_w, aw_b, dots_wt, dots_b);

    // ---- MSDeformAttn ----
    ln_bf16_kernel<<<BLTOT, 256, 0, stream>>>(query, qn_w, qn_b, q_ln);
    gemm_kernel<32, 128, 16, 64, 2><<<dim3(1, BLTOT / 32), 256, 0, stream>>>(
        q_ln, dots_wt, dots_b, nullptr, dots_out, BLTOT, 128, 768);
    locsoftmax_kernel<<<(BLTOT * NHEADS + 255) / 256, 256, 0, stream>>>(dots_out, refp, params);
    ln_bf16_kernel<<<FROWS, 256, 0, stream>>>(feat, fn_w, fn_b, f_ln);
    gemm_kernel<128, 128, 64, 64, 0><<<dim3(6, FROWS / 128), 256, 0, stream>>>(
        f_ln, vp_wt, vp_b, nullptr, value, FROWS, 768, 768);
    sampler_kernel<<<(BLTOT * NHEADS) / 16, 256, 0, stream>>>(value, params, attn_in);
    gemm_kernel<64, 128, 32, 64, 3><<<dim3(6, BLTOT / 64), 256, 0, stream>>>(
        attn_in, op_wt, op_b, query, s_bf, BLTOT, 768, 768);    // s_bf = query + attn (bf16)

    // ---- ConvFFN ----
    ln_bf16in_kernel<<<BLTOT / 4, 256, 0, stream>>>(s_bf, ffn_w, ffn_b, y);
    gemm_kernel<64, 64, 16, 64, 0><<<dim3(3, BLTOT / 64), 256, 0, stream>>>(
        y, fc1_wt, fc1_b, nullptr, z, BLTOT, HID, 768);
    dwconv_gelu_kernel<<<BLTOT / 4, 192, 0, stream>>>(z, dw_w, dw_b, g);
    gemm_kernel<64, 128, 32, 64, 4><<<dim3(6, BLTOT / 64), 256, 0, stream>>>(
        g, fc2_wt, fc2_b, s_bf, out, BLTOT, 768, HID);          // out = s_bf + ffn (f32)
}

// Round 7
// 327.245 us; speedup vs baseline: 2.0932x; 1.0480x over previous
//
#include <hip/hip_runtime.h>
#include <hip/hip_bf16.h>
#include <math.h>

typedef __hip_bfloat16 bf16;
typedef short bf16x8 __attribute__((ext_vector_type(8)));
typedef short bf16x4 __attribute__((ext_vector_type(4)));
typedef float f32x4 __attribute__((ext_vector_type(4)));

#define NB 8
#define LQ 3072
#define CC 768
#define NHEADS 6
#define NPTS 4
#define DHEAD 128
#define HLVL 64
#define WLVL 64
#define LIN 4096
#define HID 192
#define BLTOT 24576   // NB*LQ
#define FROWS 32768   // NB*LIN

__device__ __forceinline__ float bf2f(short u)
{ return __uint_as_float(((unsigned)(unsigned short)u) << 16); }

template<int N_>
__device__ __forceinline__ void wait_vmcnt()
{
    if constexpr (N_ == 0)      asm volatile("s_waitcnt vmcnt(0)" ::: "memory");
    else if constexpr (N_ == 2) asm volatile("s_waitcnt vmcnt(2)" ::: "memory");
    else if constexpr (N_ == 4) asm volatile("s_waitcnt vmcnt(4)" ::: "memory");
    else if constexpr (N_ == 6) asm volatile("s_waitcnt vmcnt(6)" ::: "memory");
    else if constexpr (N_ == 8) asm volatile("s_waitcnt vmcnt(8)" ::: "memory");
    else static_assert(N_ == 0, "add a vmcnt case");
}

// ---------------- LayerNorm (f32 in) -> bf16 out, wave per row, no barriers ----------------
__global__ __launch_bounds__(256)
void ln_f32_wave_kernel(const float* __restrict__ x, const float* __restrict__ w,
                        const float* __restrict__ b, bf16* __restrict__ out)
{
    const int row = blockIdx.x * 4 + (threadIdx.x >> 6);
    const int lane = threadIdx.x & 63;
    const f32x4* xr = (const f32x4*)(x + (size_t)row * CC);
    f32x4 f0 = xr[lane], f1 = xr[64 + lane], f2 = xr[128 + lane];
    float s = 0.f, ss = 0.f;
    #pragma unroll
    for (int k = 0; k < 4; ++k) {
        s += f0[k] + f1[k] + f2[k];
        ss += f0[k] * f0[k] + f1[k] * f1[k] + f2[k] * f2[k];
    }
    #pragma unroll
    for (int o = 32; o > 0; o >>= 1) { s += __shfl_down(s, o); ss += __shfl_down(ss, o); }
    s = __shfl(s, 0); ss = __shfl(ss, 0);
    const float m = s * (1.f / CC);
    const float rs = rsqrtf(ss * (1.f / CC) - m * m + 1e-6f);
    const f32x4* w4 = (const f32x4*)w;
    const f32x4* b4 = (const f32x4*)b;
    bf16* orow = out + (size_t)row * CC;
    #pragma unroll
    for (int j = 0; j < 3; ++j) {
        f32x4 fj = (j == 0) ? f0 : (j == 1) ? f1 : f2;
        f32x4 wj = w4[j * 64 + lane], bj = b4[j * 64 + lane];
        bf16 t4[4];
        #pragma unroll
        for (int k = 0; k < 4; ++k) t4[k] = __float2bfloat16((fj[k] - m) * rs * wj[k] + bj[k]);
        *(bf16x4*)(orow + j * 256 + lane * 4) = *(bf16x4*)t4;
    }
}

// ---------------- weight f32 (K,N) -> bf16 transposed (N,K), 64x64 LDS tiles ----------------
__global__ __launch_bounds__(256)
void wt_bf16_kernel(const float* __restrict__ src, bf16* __restrict__ dst, int K, int N)
{
    __shared__ float t[64][65];
    const int tn0 = blockIdx.x * 64, tk0 = blockIdx.y * 64;
    const int r = threadIdx.x >> 6, c = threadIdx.x & 63;
    #pragma unroll
    for (int i = 0; i < 16; ++i) {
        const int k = i * 4 + r;
        t[k][c] = src[(size_t)(tk0 + k) * N + tn0 + c];
    }
    __syncthreads();
    #pragma unroll
    for (int i = 0; i < 16; ++i) {
        const int n = i * 4 + r;
        dst[(size_t)(tn0 + n) * K + tk0 + c] = __float2bfloat16(t[c][n]);
    }
}

// ---------------- combined sampling-offset/attn-weight projection, padded to N=128 ----------------
__global__ __launch_bounds__(256)
void build_dots_w(const float* __restrict__ so_w, const float* __restrict__ so_b,
                  const float* __restrict__ aw_w, const float* __restrict__ aw_b,
                  bf16* __restrict__ wt, float* __restrict__ db)
{
    int i = blockIdx.x * 256 + threadIdx.x;  // over 128*768
    if (i < 128 * 768) {
        int n = i / 768, k = i - n * 768;
        float v = 0.f;
        if (n < 48) v = so_w[(size_t)k * 48 + n];
        else if (n < 72) v = aw_w[(size_t)k * 24 + (n - 48)];
        wt[i] = __float2bfloat16(v);
    }
    if (i < 128) {
        float bv = 0.f;
        if (i < 48) bv = so_b[i];
        else if (i < 72) bv = aw_b[i - 48];
        db[i] = bv;
    }
}

// ---------------- bf16 MFMA GEMM: C = A(M,K) * Bt(N,K)^T + bias (+res) ----------------
// MODE 0: bf16 out = acc+bias
// MODE 3: bf16 out = acc+bias+res_f32   (res prefetched to regs)
// MODE 4: f32  out = acc+bias+res_bf16  (res prefetched to regs)
template<int BM, int BN, int WM, int WN, int MODE>
__global__ __launch_bounds__(256)
void gemm_kernel(const bf16* __restrict__ A, const bf16* __restrict__ Bt,
                 const float* __restrict__ bias, const void* __restrict__ resv,
                 void* __restrict__ outv, int M, int N, int K)
{
    constexpr int WAVES_N = BN / WN;
    constexpr int FM = WM / 16, FN = WN / 16;
    constexpr int CWA = BM / 32;
    constexpr int CWB = BN / 32;
    constexpr int LPT = CWA + CWB;
    constexpr int ABYTES = BM * 256;
    constexpr int DBUF_BYTES = (BM + BN) * 256;
    constexpr int EPI_BYTES = BM * BN * 4;
    constexpr size_t SMEM_BYTES = DBUF_BYTES > EPI_BYTES ? DBUF_BYTES : EPI_BYTES;
    __shared__ __align__(16) char smem[SMEM_BYTES];
    bf16* sA = (bf16*)smem;
    bf16* sB = (bf16*)(smem + ABYTES);
    float* epi = (float*)smem;

    const int tid = threadIdx.x;
    const int lane = tid & 63;
    const int wave = tid >> 6;

    const int nwgx = gridDim.x;
    const int nwg = nwgx * gridDim.y;
    const int bid = blockIdx.y * nwgx + blockIdx.x;
    const int swz = (bid & 7) * (nwg >> 3) + (bid >> 3);
    const int m0 = (swz / nwgx) * BM;
    const int n0 = (swz % nwgx) * BN;

    const int wm = (wave / WAVES_N) * WM;
    const int wn = (wave % WAVES_N) * WN;

    const int srow = lane >> 3;
    const int scol = ((lane & 7) ^ srow) * 8;

    // ---- residual prefetch into registers (overlaps the K-loop) ----
    constexpr int GPR8 = BN / 8;
    constexpr int GPT8 = (BM * BN / 8) / 256;
    constexpr int QPR4 = BN / 4;
    constexpr int QPT4 = (BM * BN / 4) / 256;
    float4 pr0[GPT8], pr1[GPT8];
    bf16x4 prb[QPT4];
    if constexpr (MODE == 3) {
        const float* resf = (const float*)resv;
        #pragma unroll
        for (int k = 0; k < GPT8; ++k) {
            const int f = k * 256 + tid;
            const int rr = f / GPR8, cc = (f % GPR8) * 8;
            const size_t gidx = (size_t)(m0 + rr) * N + n0 + cc;
            pr0[k] = *(const float4*)&resf[gidx];
            pr1[k] = *(const float4*)&resf[gidx + 4];
        }
    }
    if constexpr (MODE == 4) {
        const bf16* resb = (const bf16*)resv;
        #pragma unroll
        for (int k = 0; k < QPT4; ++k) {
            const int f = k * 256 + tid;
            const int rr = f / QPR4, cc = (f % QPR4) * 4;
            prb[k] = *(const bf16x4*)&resb[(size_t)(m0 + rr) * N + n0 + cc];
        }
    }

#define STAGE(tt, half)                                                                            \
    { const int k0_ = (tt) * 64;                                                                   \
      _Pragma("unroll")                                                                            \
      for (int i_ = 0; i_ < CWA; ++i_) {                                                           \
        const int c_ = i_ * 4 + wave;                                                              \
        __builtin_amdgcn_global_load_lds(                                                          \
          (const __attribute__((address_space(1))) void*)(A + (size_t)(m0 + c_ * 8 + srow) * K + k0_ + scol), \
          (__attribute__((address_space(3))) void*)(sA + (half) * (BM * 64) + c_ * 512), 16, 0, 0); } \
      _Pragma("unroll")                                                                            \
      for (int i_ = 0; i_ < CWB; ++i_) {                                                           \
        const int c_ = i_ * 4 + wave;                                                              \
        __builtin_amdgcn_global_load_lds(                                                          \
          (const __attribute__((address_space(1))) void*)(Bt + (size_t)(n0 + c_ * 8 + srow) * K + k0_ + scol), \
          (__attribute__((address_space(3))) void*)(sB + (half) * (BN * 64) + c_ * 512), 16, 0, 0); } }

    f32x4 acc[FM][FN] = {};
    const int nt = K >> 6;

    STAGE(0, 0);
    STAGE(1, 1);

    for (int t = 0; t < nt; ++t) {
        const int half = t & 1;
        if (t + 1 < nt) wait_vmcnt<LPT>();
        else            wait_vmcnt<0>();
        __builtin_amdgcn_s_barrier();
        const bf16* cA = sA + half * (BM * 64);
        const bf16* cB = sB + half * (BN * 64);
        #pragma unroll
        for (int kki = 0; kki < 2; ++kki) {
            const int kslot = kki * 4 + (lane >> 4);
            bf16x8 aF[FM], bF[FN];
            #pragma unroll
            for (int i = 0; i < FM; ++i) {
                const int row = wm + i * 16 + (lane & 15);
                aF[i] = *(const bf16x8*)(&cA[row * 64 + ((kslot ^ (row & 7)) * 8)]);
            }
            #pragma unroll
            for (int j = 0; j < FN; ++j) {
                const int row = wn + j * 16 + (lane & 15);
                bF[j] = *(const bf16x8*)(&cB[row * 64 + ((kslot ^ (row & 7)) * 8)]);
            }
            #pragma unroll
            for (int i = 0; i < FM; ++i) {
                #pragma unroll
                for (int j = 0; j < FN; ++j)
                    acc[i][j] = __builtin_amdgcn_mfma_f32_16x16x32_bf16(aF[i], bF[j], acc[i][j], 0, 0, 0);
            }
        }
        asm volatile("s_waitcnt lgkmcnt(0)" ::: "memory");
        __builtin_amdgcn_s_barrier();
        if (t + 2 < nt) STAGE(t + 2, half);
    }
#undef STAGE

    // ---- epilogue: acc -> LDS (group-XOR swizzle) -> vectorized global ----
    #pragma unroll
    for (int j = 0; j < FN; ++j) {
        const int colL = wn + j * 16 + (lane & 15);
        const float bj = bias[n0 + colL];
        #pragma unroll
        for (int i = 0; i < FM; ++i) {
            #pragma unroll
            for (int r = 0; r < 4; ++r) {
                const int rowL = wm + i * 16 + ((lane >> 4) << 2) + r;
                const int addr = rowL * BN + ((((colL >> 2) ^ (rowL & 7)) << 2) | (colL & 3));
                epi[addr] = acc[i][j][r] + bj;
            }
        }
    }
    __syncthreads();

    if constexpr (MODE == 0 || MODE == 3) {
        #pragma unroll
        for (int k = 0; k < GPT8; ++k) {
            const int f = k * 256 + tid;
            const int rr = f / GPR8, cc = (f % GPR8) * 8;
            const int g0 = ((cc >> 2) ^ (rr & 7)) << 2;
            const int g1 = (((cc >> 2) + 1) ^ (rr & 7)) << 2;
            float4 v0 = *(const float4*)&epi[rr * BN + g0];
            float4 v1 = *(const float4*)&epi[rr * BN + g1];
            if constexpr (MODE == 3) {
                v0.x += pr0[k].x; v0.y += pr0[k].y; v0.z += pr0[k].z; v0.w += pr0[k].w;
                v1.x += pr1[k].x; v1.y += pr1[k].y; v1.z += pr1[k].z; v1.w += pr1[k].w;
            }
            bf16 tmp[8];
            tmp[0] = __float2bfloat16(v0.x); tmp[1] = __float2bfloat16(v0.y);
            tmp[2] = __float2bfloat16(v0.z); tmp[3] = __float2bfloat16(v0.w);
            tmp[4] = __float2bfloat16(v1.x); tmp[5] = __float2bfloat16(v1.y);
            tmp[6] = __float2bfloat16(v1.z); tmp[7] = __float2bfloat16(v1.w);
            *(bf16x8*)((bf16*)outv + (size_t)(m0 + rr) * N + n0 + cc) = *(bf16x8*)tmp;
        }
    } else {
        #pragma unroll
        for (int k = 0; k < QPT4; ++k) {
            const int f = k * 256 + tid;
            const int rr = f / QPR4, cc = (f % QPR4) * 4;
            const int gs = ((cc >> 2) ^ (rr & 7)) << 2;
            float4 v = *(const float4*)&epi[rr * BN + gs];
            if constexpr (MODE == 4) {
                v.x += bf2f(prb[k][0]); v.y += bf2f(prb[k][1]);
                v.z += bf2f(prb[k][2]); v.w += bf2f(prb[k][3]);
            }
            *(float4*)&((float*)outv)[(size_t)(m0 + rr) * N + n0 + cc] = v;
        }
    }
}

// ---------------- FUSED LayerNorm + GEMM (K=768, A resident in LDS) ----------------
// A = LN(x) computed in-kernel into swizzled LDS; B dbuf-staged via global_load_lds.
// F32IN: x is f32 (else bf16). EPI 0: bf16 out = acc+bias. EPI 1: loc-softmax -> params.
template<int BM, int BN, int WM, int WN, bool F32IN, int EPI>
__global__ __launch_bounds__(256)
void ln_gemm_kernel(const void* __restrict__ xv, const float* __restrict__ lnw,
                    const float* __restrict__ lnb, const bf16* __restrict__ Bt,
                    const float* __restrict__ bias, const float* __restrict__ refp,
                    void* __restrict__ outv, int M, int N)
{
    constexpr int WAVES_N = BN / WN;
    constexpr int FM = WM / 16, FN = WN / 16;
    constexpr int CWB = BN / 32;
    constexpr int RPW = BM / 4;
    static_assert(BM * BN * 4 <= 2 * BN * 64 * 2, "epi must fit in sB");
    __shared__ __align__(16) bf16 sA[BM * 768];
    __shared__ __align__(16) char sBmem[2 * BN * 64 * 2];
    bf16* sB = (bf16*)sBmem;
    float* epi = (float*)sBmem;

    const int tid = threadIdx.x;
    const int lane = tid & 63;
    const int wave = tid >> 6;

    const int nwgx = gridDim.x;
    const int nwg = nwgx * gridDim.y;
    const int bid = blockIdx.y * nwgx + blockIdx.x;
    const int swz = (bid & 7) * (nwg >> 3) + (bid >> 3);
    const int m0 = (swz / nwgx) * BM;
    const int n0 = (swz % nwgx) * BN;

    const int wm = (wave / WAVES_N) * WM;
    const int wn = (wave % WAVES_N) * WN;
    const int srow = lane >> 3;
    const int scol = ((lane & 7) ^ srow) * 8;

#define STAGEB(tt, half)                                                                           \
    { const int k0_ = (tt) * 64;                                                                   \
      _Pragma("unroll")                                                                            \
      for (int i_ = 0; i_ < CWB; ++i_) {                                                           \
        const int c_ = i_ * 4 + wave;                                                              \
        __builtin_amdgcn_global_load_lds(                                                          \
          (const __attribute__((address_space(1))) void*)(Bt + (size_t)(n0 + c_ * 8 + srow) * 768 + k0_ + scol), \
          (__attribute__((address_space(3))) void*)(sB + (half) * (BN * 64) + c_ * 512), 16, 0, 0); } }

    STAGEB(0, 0);
    STAGEB(1, 1);

    // ---- LN phase: each wave normalizes RPW rows into swizzled LDS A ----
    if constexpr (F32IN) {
        const f32x4* w4 = (const f32x4*)lnw;
        const f32x4* b4 = (const f32x4*)lnb;
        f32x4 wv0 = w4[lane], wv1 = w4[64 + lane], wv2 = w4[128 + lane];
        f32x4 bv0 = b4[lane], bv1 = b4[64 + lane], bv2 = b4[128 + lane];
        for (int rr = 0; rr < RPW; ++rr) {
            const int r = wave * RPW + rr;
            const f32x4* xr = (const f32x4*)((const float*)xv + (size_t)(m0 + r) * 768);
            f32x4 f0 = xr[lane], f1 = xr[64 + lane], f2 = xr[128 + lane];
            float s = 0.f, ss = 0.f;
            #pragma unroll
            for (int k = 0; k < 4; ++k) {
                s += f0[k] + f1[k] + f2[k];
                ss += f0[k] * f0[k] + f1[k] * f1[k] + f2[k] * f2[k];
            }
            #pragma unroll
            for (int o = 32; o > 0; o >>= 1) { s += __shfl_down(s, o); ss += __shfl_down(ss, o); }
            s = __shfl(s, 0); ss = __shfl(ss, 0);
            const float mn = s * (1.f / 768);
            const float rs = rsqrtf(ss * (1.f / 768) - mn * mn + 1e-6f);
            const int rx7 = r & 7;
            const int slot = (lane >> 1) & 7;
            const int off = (lane & 1) * 4;
            #pragma unroll
            for (int j = 0; j < 3; ++j) {
                f32x4 fj = (j == 0) ? f0 : (j == 1) ? f1 : f2;
                f32x4 wj = (j == 0) ? wv0 : (j == 1) ? wv1 : wv2;
                f32x4 bj = (j == 0) ? bv0 : (j == 1) ? bv1 : bv2;
                bf16 t4[4];
                #pragma unroll
                for (int k = 0; k < 4; ++k)
                    t4[k] = __float2bfloat16((fj[k] - mn) * rs * wj[k] + bj[k]);
                const int kt = j * 4 + (lane >> 4);
                *(bf16x4*)&sA[r * 768 + kt * 64 + ((slot ^ rx7) << 3) + off] = *(bf16x4*)t4;
            }
        }
    } else {
        const f32x4* w4 = (const f32x4*)lnw;
        const f32x4* b4 = (const f32x4*)lnb;
        f32x4 w80 = w4[lane * 2], w81 = w4[lane * 2 + 1], w44 = w4[128 + lane];
        f32x4 b80 = b4[lane * 2], b81 = b4[lane * 2 + 1], b44 = b4[128 + lane];
        for (int rr = 0; rr < RPW; ++rr) {
            const int r = wave * RPW + rr;
            const bf16* xr = (const bf16*)xv + (size_t)(m0 + r) * 768;
            bf16x8 v8 = *(const bf16x8*)(xr + lane * 8);
            bf16x4 v4 = *(const bf16x4*)(xr + 512 + lane * 4);
            float f[12];
            #pragma unroll
            for (int k = 0; k < 8; ++k) f[k] = bf2f(v8[k]);
            #pragma unroll
            for (int k = 0; k < 4; ++k) f[8 + k] = bf2f(v4[k]);
            float s = 0.f, ss = 0.f;
            #pragma unroll
            for (int k = 0; k < 12; ++k) { s += f[k]; ss += f[k] * f[k]; }
            #pragma unroll
            for (int o = 32; o > 0; o >>= 1) { s += __shfl_down(s, o); ss += __shfl_down(ss, o); }
            s = __shfl(s, 0); ss = __shfl(ss, 0);
            const float mn = s * (1.f / 768);
            const float rs = rsqrtf(ss * (1.f / 768) - mn * mn + 1e-6f);
            const int rx7 = r & 7;
            bf16 t8[8];
            #pragma unroll
            for (int k = 0; k < 4; ++k) t8[k] = __float2bfloat16((f[k] - mn) * rs * w80[k] + b80[k]);
            #pragma unroll
            for (int k = 0; k < 4; ++k) t8[4 + k] = __float2bfloat16((f[4 + k] - mn) * rs * w81[k] + b81[k]);
            *(bf16x8*)&sA[r * 768 + (lane >> 3) * 64 + (((lane & 7) ^ rx7) << 3)] = *(bf16x8*)t8;
            bf16 t4[4];
            #pragma unroll
            for (int k = 0; k < 4; ++k) t4[k] = __float2bfloat16((f[8 + k] - mn) * rs * w44[k] + b44[k]);
            *(bf16x4*)&sA[r * 768 + (8 + (lane >> 4)) * 64 + ((((lane >> 1) & 7) ^ rx7) << 3) + (lane & 1) * 4]
                = *(bf16x4*)t4;
        }
    }
    asm volatile("s_waitcnt lgkmcnt(0)" ::: "memory");   // LN ds_writes done before barrier

    f32x4 acc[FM][FN] = {};
    for (int t = 0; t < 12; ++t) {
        const int half = t & 1;
        if (t + 1 < 12) wait_vmcnt<CWB>();
        else            wait_vmcnt<0>();
        __builtin_amdgcn_s_barrier();
        const bf16* cB = sB + half * (BN * 64);
        #pragma unroll
        for (int kki = 0; kki < 2; ++kki) {
            const int kslot = kki * 4 + (lane >> 4);
            bf16x8 aF[FM], bF[FN];
            #pragma unroll
            for (int i = 0; i < FM; ++i) {
                const int row = wm + i * 16 + (lane & 15);
                aF[i] = *(const bf16x8*)(&sA[row * 768 + t * 64 + ((kslot ^ (row & 7)) * 8)]);
            }
            #pragma unroll
            for (int j = 0; j < FN; ++j) {
                const int row = wn + j * 16 + (lane & 15);
                bF[j] = *(const bf16x8*)(&cB[row * 64 + ((kslot ^ (row & 7)) * 8)]);
            }
            #pragma unroll
            for (int i = 0; i < FM; ++i) {
                #pragma unroll
                for (int j = 0; j < FN; ++j)
                    acc[i][j] = __builtin_amdgcn_mfma_f32_16x16x32_bf16(aF[i], bF[j], acc[i][j], 0, 0, 0);
            }
        }
        asm volatile("s_waitcnt lgkmcnt(0)" ::: "memory");
        __builtin_amdgcn_s_barrier();
        if (t + 2 < 12) STAGEB(t + 2, half);
    }
#undef STAGEB

    // ---- epilogue: acc -> epi LDS (reuses sB) ----
    #pragma unroll
    for (int j = 0; j < FN; ++j) {
        const int colL = wn + j * 16 + (lane & 15);
        const float bj = bias[n0 + colL];
        #pragma unroll
        for (int i = 0; i < FM; ++i) {
            #pragma unroll
            for (int r = 0; r < 4; ++r) {
                const int rowL = wm + i * 16 + ((lane >> 4) << 2) + r;
                const int addr = rowL * BN + ((((colL >> 2) ^ (rowL & 7)) << 2) | (colL & 3));
                epi[addr] = acc[i][j][r] + bj;
            }
        }
    }
    __syncthreads();

    if constexpr (EPI == 1) {
        // loc-softmax: thread = (rowL, head); BM=32 assumed
        if (tid < BM * NHEADS) {
            const int rowL = tid & (BM - 1);
            const int h = tid / BM;
            auto erd = [&](int col) -> float {
                return epi[rowL * BN + ((((col >> 2) ^ (rowL & 7)) << 2) | (col & 3))];
            };
            float l0 = erd(48 + h * 4 + 0), l1 = erd(48 + h * 4 + 1);
            float l2 = erd(48 + h * 4 + 2), l3 = erd(48 + h * 4 + 3);
            float mx = fmaxf(fmaxf(l0, l1), fmaxf(l2, l3));
            float e0 = expf(l0 - mx), e1 = expf(l1 - mx), e2 = expf(l2 - mx), e3 = expf(l3 - mx);
            float inv = 1.f / (e0 + e1 + e2 + e3);
            float ee[4] = {e0, e1, e2, e3};
            const float rx = refp[(size_t)(m0 + rowL) * 2];
            const float ry = refp[(size_t)(m0 + rowL) * 2 + 1];
            float4* pp = (float4*)outv + ((size_t)(m0 + rowL) * NHEADS + h) * 4;
            #pragma unroll
            for (int p = 0; p < 4; ++p) {
                float ox = erd(h * 8 + p * 2), oy = erd(h * 8 + p * 2 + 1);
                pp[p] = make_float4(rx + ox * (1.f / WLVL), ry + oy * (1.f / HLVL), ee[p] * inv, 0.f);
            }
        }
    } else {
        constexpr int GPR8 = BN / 8;
        constexpr int GPT8 = (BM * BN / 8) / 256;
        #pragma unroll
        for (int k = 0; k < GPT8; ++k) {
            const int f = k * 256 + tid;
            const int rr = f / GPR8, cc = (f % GPR8) * 8;
            const int g0 = ((cc >> 2) ^ (rr & 7)) << 2;
            const int g1 = (((cc >> 2) + 1) ^ (rr & 7)) << 2;
            float4 v0 = *(const float4*)&epi[rr * BN + g0];
            float4 v1 = *(const float4*)&epi[rr * BN + g1];
            bf16 tmp[8];
            tmp[0] = __float2bfloat16(v0.x); tmp[1] = __float2bfloat16(v0.y);
            tmp[2] = __float2bfloat16(v0.z); tmp[3] = __float2bfloat16(v0.w);
            tmp[4] = __float2bfloat16(v1.x); tmp[5] = __float2bfloat16(v1.y);
            tmp[6] = __float2bfloat16(v1.z); tmp[7] = __float2bfloat16(v1.w);
            *(bf16x8*)((bf16*)outv + (size_t)(m0 + rr) * N + n0 + cc) = *(bf16x8*)tmp;
        }
    }
}

// ---------------- bilinear sample: branchless, XCD-swizzled (image -> XCD) ----------------
__global__ __launch_bounds__(256)
void sampler_kernel(const bf16* __restrict__ value, const float4* __restrict__ params,
                    bf16* __restrict__ attn_in)
{
    const int tid = threadIdx.x;
    const int cpx = gridDim.x >> 3;                 // blocks per XCD (=1152 = blocks per image)
    const int gblk = (blockIdx.x & 7) * cpx + (blockIdx.x >> 3);
    const int g = gblk * 16 + (tid >> 4);           // query-head index = bl*NHEADS + h
    const int lane16 = tid & 15;
    const int bl = g / NHEADS;
    const int h = g - bl * NHEADS;
    const int b = bl / LQ;
    const bf16* vh = value + (size_t)b * LIN * CC + h * DHEAD + lane16 * 8;

    int offs[16];
    float wgt[16];
    #pragma unroll
    for (int p = 0; p < NPTS; ++p) {
        float4 pr = params[(size_t)g * 4 + p];
        float x = pr.x * (float)WLVL - 0.5f;
        float y = pr.y * (float)HLVL - 0.5f;
        float x0f = floorf(x), y0f = floorf(y);
        float wx1 = x - x0f, wy1 = y - y0f;
        float wx0 = 1.f - wx1, wy0 = 1.f - wy1;
        int x0 = (int)x0f, y0 = (int)y0f;
        #pragma unroll
        for (int dy = 0; dy < 2; ++dy) {
            const int yi = y0 + dy;
            const int yc = min(max(yi, 0), HLVL - 1);
            const float wy = (dy ? wy1 : wy0) * ((yi >= 0 && yi < HLVL) ? pr.z : 0.f);
            #pragma unroll
            for (int dx = 0; dx < 2; ++dx) {
                const int xi = x0 + dx;
                const int xc = min(max(xi, 0), WLVL - 1);
                const int idx = p * 4 + dy * 2 + dx;
                offs[idx] = (yc * WLVL + xc) * CC;
                wgt[idx] = wy * (dx ? wx1 : wx0) * ((xi >= 0 && xi < WLVL) ? 1.f : 0.f);
            }
        }
    }
    bf16x8 v[16];
    #pragma unroll
    for (int i = 0; i < 16; ++i) v[i] = *(const bf16x8*)(vh + offs[i]);
    float acc[8] = {};
    #pragma unroll
    for (int i = 0; i < 16; ++i) {
        #pragma unroll
        for (int j = 0; j < 8; ++j)
            acc[j] += wgt[i] * bf2f(v[i][j]);
    }
    bf16 tmp[8];
    #pragma unroll
    for (int j = 0; j < 8; ++j) tmp[j] = __float2bfloat16(acc[j]);
    *(bf16x8*)(attn_in + (size_t)bl * CC + h * DHEAD + lane16 * 8) = *(bf16x8*)tmp;
}

// ---------------- depthwise 3x3 conv + bias + exact GELU (bf16 in/out, 4ch/thread) ----------------
__global__ __launch_bounds__(192)
void dwconv_gelu_kernel(const bf16* __restrict__ z, const float* __restrict__ dw_w,
                        const float* __restrict__ dw_b, bf16* __restrict__ g)
{
    const int tp = threadIdx.x / 48;            // pixel within block (4)
    const int tc = threadIdx.x % 48;            // channel group
    const int m = blockIdx.x * 4 + tp;
    const int c = tc * 4;
    const int pix = m & 1023;
    const int h = pix >> 5, w = pix & 31;
    float acc[4];
    #pragma unroll
    for (int j = 0; j < 4; ++j) acc[j] = dw_b[c + j];
    #pragma unroll
    for (int dy = -1; dy <= 1; ++dy) {
        int hh2 = h + dy;
        if (hh2 < 0 || hh2 >= 32) continue;
        #pragma unroll
        for (int dx = -1; dx <= 1; ++dx) {
            int ww2 = w + dx;
            if (ww2 < 0 || ww2 >= 32) continue;
            bf16x4 vv = *(const bf16x4*)&z[(size_t)(m + dy * 32 + dx) * HID + c];
            #pragma unroll
            for (int j = 0; j < 4; ++j)
                acc[j] += bf2f(vv[j]) * dw_w[(c + j) * 9 + (dy + 1) * 3 + (dx + 1)];
        }
    }
    bf16 tmp[4];
    #pragma unroll
    for (int j = 0; j < 4; ++j) {
        float ge = acc[j] * 0.5f * (1.f + erff(acc[j] * 0.70710678118f));
        tmp[j] = __float2bfloat16(ge);
    }
    *(bf16x4*)&g[(size_t)m * HID + c] = *(bf16x4*)tmp;
}

extern "C" void kernel_launch(void* const* d_in, const int* in_sizes, int n_in,
                              void* d_out, int out_size, void* d_ws, size_t ws_size,
                              hipStream_t stream)
{
    const float* query = (const float*)d_in[0];
    const float* refp  = (const float*)d_in[1];
    const float* feat  = (const float*)d_in[2];
    const float* qn_w = (const float*)d_in[7];
    const float* qn_b = (const float*)d_in[8];
    const float* fn_w = (const float*)d_in[9];
    const float* fn_b = (const float*)d_in[10];
    const float* so_w = (const float*)d_in[11];
    const float* so_b = (const float*)d_in[12];
    const float* aw_w = (const float*)d_in[13];
    const float* aw_b = (const float*)d_in[14];
    const float* vp_w = (const float*)d_in[15];
    const float* vp_b = (const float*)d_in[16];
    const float* op_w = (const float*)d_in[17];
    const float* op_b = (const float*)d_in[18];
    const float* ffn_w = (const float*)d_in[19];
    const float* ffn_b = (const float*)d_in[20];
    const float* fc1_w = (const float*)d_in[21];
    const float* fc1_b = (const float*)d_in[22];
    const float* dw_w = (const float*)d_in[23];
    const float* dw_b = (const float*)d_in[24];
    const float* fc2_w = (const float*)d_in[25];
    const float* fc2_b = (const float*)d_in[26];
    float* out = (float*)d_out;

    // ---- workspace layout (all 256B aligned) ----
    if (ws_size < (size_t)125829632) return;    // need ~126MB
    char* ws = (char*)d_ws;
    bf16* vp_wt   = (bf16*)(ws + 0);            // 768x768
    bf16* op_wt   = (bf16*)(ws + 1179648);      // 768x768
    bf16* fc1_wt  = (bf16*)(ws + 2359296);      // 192x768
    bf16* fc2_wt  = (bf16*)(ws + 2654208);      // 768x192
    bf16* dots_wt = (bf16*)(ws + 2949120);      // 128x768
    float* dots_b = (float*)(ws + 3145728);     // 128
    char* paramsR = ws + 3146240;               // 9.4MB: params -> g
    char* dotsR   = ws + 12583424;              // 12.6MB: z
    char* regA = ws + 25166336;                 // 50.3MB: f_ln -> attn_in
    char* regB = ws + 75497984;                 // 50.3MB: value -> s_bf
    float4* params = (float4*)paramsR;
    bf16* g        = (bf16*)paramsR;
    bf16* z        = (bf16*)dotsR;
    bf16* f_ln    = (bf16*)regA;
    bf16* attn_in = (bf16*)regA;
    bf16* value = (bf16*)regB;
    bf16* s_bf  = (bf16*)regB;

    // ---- weight prep (bf16, transposed to (N,K)) ----
    wt_bf16_kernel<<<dim3(12, 12), 256, 0, stream>>>(vp_w, vp_wt, 768, 768);
    wt_bf16_kernel<<<dim3(12, 12), 256, 0, stream>>>(op_w, op_wt, 768, 768);
    wt_bf16_kernel<<<dim3(3, 12), 256, 0, stream>>>(fc1_w, fc1_wt, 768, 192);
    wt_bf16_kernel<<<dim3(12, 3), 256, 0, stream>>>(fc2_w, fc2_wt, 192, 768);
    build_dots_w<<<384, 256, 0, stream>>>(so_w, so_b, aw_w, aw_b, dots_wt, dots_b);

    // ---- MSDeformAttn ----
    // fused LN(query) + offsets/weights projection + loc-softmax -> params
    ln_gemm_kernel<32, 128, 16, 64, true, 1><<<dim3(1, BLTOT / 32), 256, 0, stream>>>(
        query, qn_w, qn_b, dots_wt, dots_b, refp, params, BLTOT, 128);
    ln_f32_wave_kernel<<<FROWS / 4, 256, 0, stream>>>(feat, fn_w, fn_b, f_ln);
    gemm_kernel<128, 128, 64, 64, 0><<<dim3(6, FROWS / 128), 256, 0, stream>>>(
        f_ln, vp_wt, vp_b, nullptr, value, FROWS, 768, 768);
    sampler_kernel<<<(BLTOT * NHEADS) / 16, 256, 0, stream>>>(value, params, attn_in);
    gemm_kernel<64, 128, 32, 64, 3><<<dim3(6, BLTOT / 64), 256, 0, stream>>>(
        attn_in, op_wt, op_b, query, s_bf, BLTOT, 768, 768);    // s_bf = query + attn (bf16)

    // ---- ConvFFN ----
    // fused LN(s_bf) + fc1 -> z (bf16)
    ln_gemm_kernel<32, 64, 32, 16, false, 0><<<dim3(3, BLTOT / 32), 256, 0, stream>>>(
        s_bf, ffn_w, ffn_b, fc1_wt, fc1_b, nullptr, z, BLTOT, HID);
    dwconv_gelu_kernel<<<BLTOT / 4, 192, 0, stream>>>(z, dw_w, dw_b, g);
    gemm_kernel<64, 128, 32, 64, 4><<<dim3(6, BLTOT / 64), 256, 0, stream>>>(
        g, fc2_wt, fc2_b, s_bf, out, BLTOT, 768, HID);          // out = s_bf + ffn (f32)
}